// Round 10
// baseline (2922.229 us; speedup 1.0000x reference)
//
#include <hip/hip_runtime.h>

#define NB 1024
#define SL 300
#define NT 150
#define NH 256
#define LA 320
#define NV 81
#define NR 8      // batch rows per block
#define NBLK 128  // blocks
#define HST 272   // f16 row stride: uniform 2-way LDS banking on MFMA A-reads (free)

typedef _Float16 f16;
typedef _Float16 f16x2 __attribute__((ext_vector_type(2)));
typedef _Float16 f16x4 __attribute__((ext_vector_type(4)));
typedef _Float16 f16x8 __attribute__((ext_vector_type(8)));
typedef float    f32x4 __attribute__((ext_vector_type(4)));

// ws float offsets
#define OFF_WATT    0u
#define OFF_WCOMBT  163840u
#define OFF_P1B     294912u
#define OFF_P2B     320832u
#define OFF_Q2T     341568u
#define OFF_Q2PE    362304u
#define OFF_PE      362560u
#define OFF_Q2TPH   362816u    // f16 [21][1024] panels of Q2T (occupies 10752 floats)
#define OFF_WCATM   384320u    // f16 [64 nt][16 kw][64 lane][8]
#define OFF_WATTM   646464u    // f16 [20 nt][8 kw][64 lane][8]
#define OFF_WFCPH   687424u    // f16 [32][81][8]
#define OFF_LOSS    697792u

static __device__ __forceinline__ float rcpf(float x)  { return __builtin_amdgcn_rcpf(x); }
static __device__ __forceinline__ float sigm(float x)  { return rcpf(1.f + __expf(-x)); }
static __device__ __forceinline__ float tanhf_(float x){ return 1.f - 2.f * rcpf(1.f + __expf(2.f * x)); }

static __device__ __forceinline__ float dot2(f16x2 a, f16x2 b, float c) {
#if __has_builtin(__builtin_amdgcn_fdot2)
    return __builtin_amdgcn_fdot2(a, b, c, false);
#else
    return c + (float)a[0] * (float)b[0] + (float)a[1] * (float)b[1];
#endif
}
#define DOT4(wf4, af4, acc) { \
    acc = dot2(__builtin_bit_cast(f16x2, (wf4).x), __builtin_bit_cast(f16x2, (af4).x), acc); \
    acc = dot2(__builtin_bit_cast(f16x2, (wf4).y), __builtin_bit_cast(f16x2, (af4).y), acc); \
    acc = dot2(__builtin_bit_cast(f16x2, (wf4).z), __builtin_bit_cast(f16x2, (af4).z), acc); \
    acc = dot2(__builtin_bit_cast(f16x2, (wf4).w), __builtin_bit_cast(f16x2, (af4).w), acc); }

static __device__ __forceinline__ void ctr_add(int* p) {
    if ((threadIdx.x & 63) == 0)
        __hip_atomic_fetch_add(p, 1, __ATOMIC_RELEASE, __HIP_MEMORY_SCOPE_WORKGROUP);
}
static __device__ __forceinline__ void ctr_spin(int* p, int target) {
    while (__hip_atomic_load(p, __ATOMIC_ACQUIRE, __HIP_MEMORY_SCOPE_WORKGROUP) < target)
        __builtin_amdgcn_s_sleep(1);
}

// ---------------- setup kernels ----------------
__global__ __launch_bounds__(128) void k_pe(float* __restrict__ pe) {
    const int i = threadIdx.x;
    const float arg  = (float)(2 * i) * (-0.035977892078031968f);
    const float divf = expf(arg) * 300.0f;
    pe[2 * i]     = (float)sin((double)divf);
    pe[2 * i + 1] = (float)cos((double)divf);
}
__global__ __launch_bounds__(256) void k_tr_att(const float* __restrict__ W, float* __restrict__ WT) {
    const int i = blockIdx.x * 256 + threadIdx.x;
    if (i < 512 * LA) { const int k = i / LA, l = i - k * LA; WT[i] = W[l * 512 + k]; }
}
__global__ __launch_bounds__(256) void k_tr_comb(const float* __restrict__ W, float* __restrict__ WT) {
    const int i = blockIdx.x * 256 + threadIdx.x;
    const int k = i >> 8, j = i & 255;
    if (i < 512 * NH) WT[i] = W[j * 512 + k];
}
__global__ __launch_bounds__(320) void k_p1b(const float* __restrict__ emb, const float* __restrict__ WATT,
                                             const float* __restrict__ b_att, float* __restrict__ P1B) {
    __shared__ float e[NH];
    const int v = blockIdx.x, tid = threadIdx.x;
    if (tid < NH) e[tid] = emb[v * NH + tid];
    __syncthreads();
    float a = b_att[tid];
    #pragma unroll 8
    for (int k = 0; k < NH; ++k) a += e[k] * WATT[k * LA + tid];
    P1B[v * LA + tid] = a;
}
__global__ __launch_bounds__(256) void k_p2q(const float* __restrict__ emb, const float* __restrict__ WCOMBT,
                                             const float* __restrict__ b_comb,
                                             float* __restrict__ P2B, float* __restrict__ Q2T) {
    __shared__ float e[NH];
    const int v = blockIdx.x, tid = threadIdx.x;
    e[tid] = emb[v * NH + tid];
    __syncthreads();
    float a = b_comb[tid], q = 0.f;
    #pragma unroll 8
    for (int k = 0; k < NH; ++k) {
        a += e[k] * WCOMBT[k * NH + tid];
        q += e[k] * WCOMBT[(NH + k) * NH + tid];
    }
    P2B[v * NH + tid] = a;
    Q2T[v * NH + tid] = q;
}
__global__ __launch_bounds__(256) void k_q2pe(const float* __restrict__ pe, const float* __restrict__ WCOMBT,
                                              float* __restrict__ Q2PE) {
    __shared__ float e[NH];
    const int tid = threadIdx.x;
    e[tid] = pe[tid];
    __syncthreads();
    float q = 0.f;
    #pragma unroll 8
    for (int k = 0; k < NH; ++k) q += e[k] * WCOMBT[(NH + k) * NH + tid];
    Q2PE[tid] = q;
}
__global__ __launch_bounds__(256) void k_pan_q2h(const float* __restrict__ Q2T, f16* __restrict__ P) {
    const int i = blockIdx.x * 256 + threadIdx.x;
    if (i < NV * NH) {
        const int v = i >> 8, j = i & 255;
        P[(v >> 2) * 1024 + j * 4 + (v & 3)] = (f16)Q2T[v * NH + j];
    }
}
__global__ __launch_bounds__(256) void k_pan_cat_m(const float* __restrict__ Wih, const float* __restrict__ Whh,
                                                   f16* __restrict__ P) {
    const int i = blockIdx.x * 256 + threadIdx.x;
    if (i < 512 * 1024) {
        const int k = i >> 10, c = i & 1023, jcol = c >> 2, g = c & 3;
        const float v = (k < NH) ? Wih[(g * NH + jcol) * NH + k] : Whh[(g * NH + jcol) * NH + (k - NH)];
        const int nt = c >> 4, kw = k >> 5, kr = k & 31;
        const int l = (kr >> 3) * 16 + (c & 15), jj = kr & 7;
        P[nt * 8192 + kw * 512 + l * 8 + jj] = (f16)v;
    }
}
__global__ __launch_bounds__(256) void k_pan_att_m(const float* __restrict__ W, f16* __restrict__ P) {
    const int i = blockIdx.x * 256 + threadIdx.x;
    if (i < 256 * LA) {
        const int k = i / LA, lcol = i - k * LA;
        const float v = W[lcol * 512 + 256 + k];
        const int nt = lcol >> 4, kw = k >> 5, kr = k & 31;
        const int l = (kr >> 3) * 16 + (lcol & 15), jj = kr & 7;
        P[nt * 4096 + kw * 512 + l * 8 + jj] = (f16)v;
    }
}
__global__ __launch_bounds__(256) void k_pan_fc_h(const float* __restrict__ W, f16* __restrict__ P) {
    const int i = blockIdx.x * 256 + threadIdx.x;
    if (i < 256 * NV) {
        const int k = i / NV, v = i - k * NV;
        P[(k >> 3) * 648 + v * 8 + (k & 7)] = (f16)W[v * NH + k];
    }
}

// ---------------- persistent decoder: 128 blocks x 1024 thr, 8 rows/block, wave-specialized ----------------
__global__ __launch_bounds__(1024, 4) void k_run(
    const int* __restrict__ enc, const int* __restrict__ tgt,
    const f16* __restrict__ WATTM, const float* __restrict__ P1B,
    const float* __restrict__ P2B, const f16* __restrict__ Q2TPH,
    const float* __restrict__ Q2PE, const f16* __restrict__ WCATM,
    const f16* __restrict__ WFCPH,
    const float* __restrict__ bih, const float* __restrict__ bhh,
    const float* __restrict__ bfc, float* __restrict__ out_logits,
    float* __restrict__ loss_out)
{
    __shared__ __attribute__((aligned(16))) f16 hbufh[2][NR][HST];
    __shared__ __attribute__((aligned(16))) f16 xh[NR][HST];
    __shared__ __attribute__((aligned(16))) f16 q2lds[21 * 1024];
    __shared__ float q2pe_lds[NH];
    __shared__ float p_s[NR][324];
    __shared__ float gex[NR][1040];
    __shared__ float bsum_lds[1024];
    __shared__ f16  cwh[NR][84];
    __shared__ float lg_s[NR][84];
    __shared__ float sm_inv[NR], sm_s300[NR];
    __shared__ unsigned short idx16[NR][SL];
    __shared__ unsigned short cnt16[NR][NV];
    __shared__ unsigned short offs16[NR][NV + 1];
    __shared__ float bfc_s[84];
    __shared__ float loss_s[NR];
    __shared__ int   xd_s[NR];
    __shared__ int   c_aP1, c_aSM, c_xr, c_gd, c_hr;

    const int tid  = threadIdx.x;
    const int wid  = tid >> 6;
    const int lane = tid & 63;
    const int mrow = lane & 15;
    const int arow8 = mrow & 7;     // A-row folded to 8 real rows
    const int khi  = lane >> 4;
    const int row0 = blockIdx.x * NR;

    // ---- one-time init (barriers allowed here) ----
    {
        f16* hz = &hbufh[0][0][0];
        for (int i = tid; i < 2 * NR * HST; i += 1024) hz[i] = (f16)0.f;
    }
    { const int c = tid, j = c >> 2, g = c & 3; bsum_lds[c] = bih[g * NH + j] + bhh[g * NH + j]; }
    if (tid < 84) bfc_s[tid] = (tid < NV) ? bfc[tid] : 0.f;
    if (tid < NR) { xd_s[tid] = 1; loss_s[tid] = 0.f; }
    if (tid == 0) { c_aP1 = 0; c_aSM = 0; c_xr = 0; c_gd = 0; c_hr = 0; }
    for (int i = tid; i < 2688; i += 1024)
        ((f16x8*)q2lds)[i] = ((const f16x8*)Q2TPH)[i];
    if (tid < NH) q2pe_lds[tid] = Q2PE[tid];
    {
        const int rg = tid >> 7, jg = tid & 127;       // 8 rows x 128 threads
        const int* __restrict__ encr = enc + (row0 + rg) * SL;
        if (jg < NV) {
            int c = 0;
            for (int l = 0; l < SL; ++l) c += (encr[l] == jg);
            cnt16[rg][jg] = (unsigned short)c;
        }
        __syncthreads();
        if (jg == 0) {
            int o = 0; offs16[rg][0] = 0;
            for (int v = 0; v < NV; ++v) { o += cnt16[rg][v]; offs16[rg][v + 1] = (unsigned short)o; }
        }
        __syncthreads();
        if (jg < NV) {
            int o = offs16[rg][jg];
            for (int l = 0; l < SL; ++l) if (encr[l] == jg) idx16[rg][o++] = (unsigned short)l;
        }
    }
    __syncthreads();

    if (wid >= 8) {
        // ================= GATES WAVES (wid 8..15) =================
        const int nt0 = (wid - 8) * 8;
        for (int t = 0; t < NT; ++t) {
            const int pb = t & 1;
            ctr_spin(&c_hr, 8 * t);
            f32x4 acc[8];
            #pragma unroll
            for (int i = 0; i < 8; ++i) acc[i] = (f32x4){0.f, 0.f, 0.f, 0.f};
            {   // h-half: kw 8..15
                const f16* __restrict__ hr = &hbufh[pb][arow8][khi * 8];
                const f16* __restrict__ B  = WCATM + (size_t)nt0 * 8192 + lane * 8;
                #pragma unroll 2
                for (int kw = 8; kw < 16; ++kw) {
                    const f16x8 a = *(const f16x8*)(hr + (kw - 8) * 32);
                    const f16* bp = B + kw * 512;
                    #pragma unroll
                    for (int i = 0; i < 8; ++i)
                        acc[i] = __builtin_amdgcn_mfma_f32_16x16x32_f16(
                            a, *(const f16x8*)(bp + (size_t)i * 8192), acc[i], 0, 0, 0);
                }
            }
            ctr_spin(&c_xr, 8 * (t + 1));
            {   // x-half: kw 0..7
                const f16* __restrict__ xr = &xh[arow8][khi * 8];
                const f16* __restrict__ B  = WCATM + (size_t)nt0 * 8192 + lane * 8;
                #pragma unroll 2
                for (int kw = 0; kw < 8; ++kw) {
                    const f16x8 a = *(const f16x8*)(xr + kw * 32);
                    const f16* bp = B + kw * 512;
                    #pragma unroll
                    for (int i = 0; i < 8; ++i)
                        acc[i] = __builtin_amdgcn_mfma_f32_16x16x32_f16(
                            a, *(const f16x8*)(bp + (size_t)i * 8192), acc[i], 0, 0, 0);
                }
            }
            if (lane < 32) {   // rows khi*4+i (0..7)
                #pragma unroll
                for (int i = 0; i < 8; ++i) {
                    const int cc = (nt0 + i) * 16 + mrow;
                    #pragma unroll
                    for (int j = 0; j < 4; ++j) gex[khi * 4 + j][cc] = acc[i][j];
                }
            }
            ctr_add(&c_gd);
        }
    } else {
        // ================= ATTENTION / VALU WAVES (wid 0..7) =================
        const int w = wid;
        float creg[4] = {0.f, 0.f, 0.f, 0.f};    // cell state: row tid>>6, units (tid&63)*4+k
        for (int t = 0; t < NT; ++t) {
            const int pb = t & 1;
            ctr_spin(&c_hr, 8 * t);
            // ---- P1: attention MFMA, wave w owns nt {w, w+8, (+w+16 if w<4)} ----
            {
                f32x4 z0 = {0.f,0.f,0.f,0.f}, z1 = {0.f,0.f,0.f,0.f}, z2 = {0.f,0.f,0.f,0.f};
                const bool three = (w < 4);
                const f16* __restrict__ B0 = WATTM + w * 4096 + lane * 8;
                const f16* __restrict__ B1 = WATTM + (8 + w) * 4096 + lane * 8;
                const f16* __restrict__ B2 = WATTM + (16 + w) * 4096 + lane * 8;
                const f16* __restrict__ hr = &hbufh[pb][arow8][khi * 8];
                #pragma unroll 2
                for (int kw = 0; kw < 8; ++kw) {
                    const f16x8 a = *(const f16x8*)(hr + kw * 32);
                    z0 = __builtin_amdgcn_mfma_f32_16x16x32_f16(a, *(const f16x8*)(B0 + kw * 512), z0, 0, 0, 0);
                    z1 = __builtin_amdgcn_mfma_f32_16x16x32_f16(a, *(const f16x8*)(B1 + kw * 512), z1, 0, 0, 0);
                    if (three)
                        z2 = __builtin_amdgcn_mfma_f32_16x16x32_f16(a, *(const f16x8*)(B2 + kw * 512), z2, 0, 0, 0);
                }
                if (lane < 32) {   // rows khi*4+i
                    #pragma unroll
                    for (int i = 0; i < 4; ++i) {
                        const int rr = khi * 4 + i;
                        p_s[rr][w * 16 + mrow]       = z0[i];
                        p_s[rr][(8 + w) * 16 + mrow] = z1[i];
                        if (three) p_s[rr][(16 + w) * 16 + mrow] = z2[i];
                    }
                }
            }
            ctr_add(&c_aP1);
            // ---- softmax + binning: wave w owns row w ----
            {
                ctr_spin(&c_aP1, 8 * (t + 1));
                const int r = w;
                const float* __restrict__ P1r = P1B + xd_s[r] * LA;
                float zv[5];
                #pragma unroll
                for (int i = 0; i < 5; ++i) zv[i] = p_s[r][lane + 64 * i] + P1r[lane + 64 * i];
                float m = fmaxf(fmaxf(fmaxf(zv[0], zv[1]), fmaxf(zv[2], zv[3])), zv[4]);
                #pragma unroll
                for (int off = 32; off > 0; off >>= 1) m = fmaxf(m, __shfl_xor(m, off));
                float sa = 0.f;
                #pragma unroll
                for (int i = 0; i < 5; ++i) {
                    zv[i] = __expf(zv[i] - m);
                    p_s[r][lane + 64 * i] = zv[i];
                    sa += zv[i];
                }
                float sh = (lane >= 44) ? zv[4] : 0.f;     // l in [300,320)
                #pragma unroll
                for (int off = 32; off > 0; off >>= 1) { sa += __shfl_xor(sa, off); sh += __shfl_xor(sh, off); }
                {   // bins 0..63
                    const int o0 = offs16[r][lane], o1 = offs16[r][lane + 1];
                    float s = 0.f;
                    for (int o = o0; o < o1; ++o) s += p_s[r][idx16[r][o]];
                    cwh[r][lane] = (f16)s;
                }
                if (lane < NV - 64) {   // bins 64..80
                    const int b2 = 64 + lane;
                    const int o0 = offs16[r][b2], o1 = offs16[r][b2 + 1];
                    float s = 0.f;
                    for (int o = o0; o < o1; ++o) s += p_s[r][idx16[r][o]];
                    cwh[r][b2] = (f16)s;
                }
                if (lane == 0) { sm_inv[r] = 1.0f / sa; sm_s300[r] = sa - sh; }
                ctr_add(&c_aSM);
            }
            ctr_spin(&c_aSM, 8 * (t + 1));
            // ---- phase 2: x (2048 items over 512 threads, LDS q2/cw via dot2) ----
            #pragma unroll
            for (int half = 0; half < 4; ++half) {
                const int item = tid + half * 512;
                const int r = item >> 8, j = item & 255;
                float acc = 0.f;
                const f16* __restrict__ cwr = cwh[r];
                #pragma unroll 5
                for (int vb = 0; vb < 20; ++vb) {
                    const f16x4 qv = *(const f16x4*)(q2lds + vb * 1024 + j * 4);
                    const f16x4 cv = *(const f16x4*)(cwr + vb * 4);
                    acc = dot2(__builtin_shufflevector(qv, qv, 0, 1),
                               __builtin_shufflevector(cv, cv, 0, 1), acc);
                    acc = dot2(__builtin_shufflevector(qv, qv, 2, 3),
                               __builtin_shufflevector(cv, cv, 2, 3), acc);
                }
                acc += (float)cwr[80] * (float)q2lds[20 * 1024 + j * 4];
                const float xv = fmaxf(P2B[xd_s[r] * NH + j]
                                       + (acc + sm_s300[r] * q2pe_lds[j]) * sm_inv[r], 0.f);
                xh[r][j] = (f16)xv;
            }
            ctr_add(&c_xr);
            // ---- LSTM pointwise: thread = (row tid>>6, 4 consecutive units) ----
            ctr_spin(&c_gd, 8 * (t + 1));
            {
                const int r = tid >> 6, u0 = (tid & 63) * 4;
                #pragma unroll
                for (int k = 0; k < 4; ++k) {
                    const float4 g4 = *(const float4*)(&gex[r][(u0 + k) * 4]);
                    const float4 b4 = *(const float4*)(&bsum_lds[(u0 + k) * 4]);
                    creg[k] = sigm(g4.y + b4.y) * creg[k] + sigm(g4.x + b4.x) * tanhf_(g4.z + b4.z);
                    hbufh[pb ^ 1][r][u0 + k] = (f16)(sigm(g4.w + b4.w) * tanhf_(creg[k]));
                }
            }
            ctr_add(&c_hr);
            // ---- fc + argmax + loss: wave w owns row w (h row w written by this wave) ----
            {
                const int r = w;
                const f16* __restrict__ hr = &hbufh[pb ^ 1][r][0];
                const int v1 = lane;
                float a1 = 0.f;
                {
                    const f16* __restrict__ wp = WFCPH + v1 * 8;
                    #pragma unroll 4
                    for (int kb = 0; kb < 32; ++kb) {
                        const float4 wv = *(const float4*)(wp + kb * 648);
                        const float4 hv = *(const float4*)(hr + kb * 8);
                        DOT4(wv, hv, a1);
                    }
                }
                const float lv1 = a1 + bfc_s[v1];
                lg_s[r][v1] = lv1;
                if (v1 < NV) out_logits[((size_t)t * NB + row0 + r) * NV + v1] = lv1;
                if (lane < NV - 64) {
                    const int v2 = 64 + lane;
                    float a2 = 0.f;
                    const f16* __restrict__ wp = WFCPH + v2 * 8;
                    #pragma unroll 4
                    for (int kb = 0; kb < 32; ++kb) {
                        const float4 wv = *(const float4*)(wp + kb * 648);
                        const float4 hv = *(const float4*)(hr + kb * 8);
                        DOT4(wv, hv, a2);
                    }
                    const float lv2 = a2 + bfc_s[v2];
                    lg_s[r][v2] = lv2;
                    out_logits[((size_t)t * NB + row0 + r) * NV + v2] = lv2;
                }
                float v0 = lg_s[r][lane]; int i0 = lane;
                if (lane < NV - 64) {
                    const float vb = lg_s[r][64 + lane];
                    if (vb > v0) { v0 = vb; i0 = 64 + lane; }
                }
                #pragma unroll
                for (int off = 32; off > 0; off >>= 1) {
                    const float vo = __shfl_xor(v0, off);
                    const int   io = __shfl_xor(i0, off);
                    if (vo > v0 || (vo == v0 && io < i0)) { v0 = vo; i0 = io; }
                }
                float e = __expf(lg_s[r][lane] - v0);
                if (lane < NV - 64) e += __expf(lg_s[r][64 + lane] - v0);
                #pragma unroll
                for (int off = 32; off > 0; off >>= 1) e += __shfl_xor(e, off);
                if (lane == 0) {
                    const int y = tgt[(row0 + r) * NT + t];
                    loss_s[r] += -(lg_s[r][y] - v0 - logf(e));
                    xd_s[r] = i0;
                }
            }
        }
        if (tid < NR) loss_out[row0 + tid] = loss_s[tid];
    }
}

// ---------------- final mean ----------------
__global__ __launch_bounds__(256) void k_final(const float* __restrict__ loss, float* __restrict__ dst) {
    const int tid = threadIdx.x;
    float v = loss[tid] + loss[tid + 256] + loss[tid + 512] + loss[tid + 768];
    #pragma unroll
    for (int o = 32; o > 0; o >>= 1) v += __shfl_xor(v, o);
    __shared__ float red[4];
    if ((tid & 63) == 0) red[tid >> 6] = v;
    __syncthreads();
    if (tid == 0) dst[0] = (red[0] + red[1] + red[2] + red[3]) / (float)(NB * NT);
}

extern "C" void kernel_launch(void* const* d_in, const int* in_sizes, int n_in,
                              void* d_out, int out_size, void* d_ws, size_t ws_size,
                              hipStream_t stream) {
    const int*   enc    = (const int*)d_in[0];
    const int*   tgt    = (const int*)d_in[1];
    const float* emb    = (const float*)d_in[3];
    const float* W_att  = (const float*)d_in[4];
    const float* b_att  = (const float*)d_in[5];
    const float* W_comb = (const float*)d_in[6];
    const float* b_comb = (const float*)d_in[7];
    const float* W_ih   = (const float*)d_in[8];
    const float* b_ih   = (const float*)d_in[9];
    const float* W_hh   = (const float*)d_in[10];
    const float* b_hh   = (const float*)d_in[11];
    const float* W_fc   = (const float*)d_in[12];
    const float* b_fc   = (const float*)d_in[13];

    float* ws  = (float*)d_ws;
    float* out = (float*)d_out;
    f16* WCATM  = (f16*)(ws + OFF_WCATM);
    f16* WATTM  = (f16*)(ws + OFF_WATTM);
    f16* WFCPH  = (f16*)(ws + OFF_WFCPH);
    f16* Q2TPH  = (f16*)(ws + OFF_Q2TPH);

    hipLaunchKernelGGL(k_pe,      dim3(1),    dim3(128), 0, stream, ws + OFF_PE);
    hipLaunchKernelGGL(k_tr_att,  dim3(640),  dim3(256), 0, stream, W_att,  ws + OFF_WATT);
    hipLaunchKernelGGL(k_tr_comb, dim3(512),  dim3(256), 0, stream, W_comb, ws + OFF_WCOMBT);
    hipLaunchKernelGGL(k_p1b,     dim3(81),   dim3(320), 0, stream, emb, ws + OFF_WATT, b_att, ws + OFF_P1B);
    hipLaunchKernelGGL(k_p2q,     dim3(81),   dim3(256), 0, stream, emb, ws + OFF_WCOMBT, b_comb,
                       ws + OFF_P2B, ws + OFF_Q2T);
    hipLaunchKernelGGL(k_q2pe,    dim3(1),    dim3(256), 0, stream, ws + OFF_PE, ws + OFF_WCOMBT, ws + OFF_Q2PE);
    hipLaunchKernelGGL(k_pan_q2h, dim3(81),   dim3(256), 0, stream, ws + OFF_Q2T, Q2TPH);
    hipLaunchKernelGGL(k_pan_cat_m, dim3(2048), dim3(256), 0, stream, W_ih, W_hh, WCATM);
    hipLaunchKernelGGL(k_pan_att_m, dim3(320),  dim3(256), 0, stream, W_att, WATTM);
    hipLaunchKernelGGL(k_pan_fc_h,  dim3(81),   dim3(256), 0, stream, W_fc, WFCPH);

    hipLaunchKernelGGL(k_run, dim3(NBLK), dim3(1024), 0, stream,
                       enc, tgt,
                       WATTM, ws + OFF_P1B, ws + OFF_P2B,
                       Q2TPH, ws + OFF_Q2PE, WCATM, WFCPH,
                       b_ih, b_hh, b_fc,
                       out, ws + OFF_LOSS);

    hipLaunchKernelGGL(k_final, dim3(1), dim3(256), 0, stream, ws + OFF_LOSS, out + (out_size - 1));
}

// Round 11
// 2763.060 us; speedup vs baseline: 1.0576x; 1.0576x over previous
//
#include <hip/hip_runtime.h>
#include <hip/hip_fp8.h>

#define NB 1024
#define SL 300
#define NT 150
#define NH 256
#define LA 320
#define NV 81
#define HST 272   // f16 row stride (halves): 136 words -> uniform 2-way banking on MFMA A-reads (free)
#define BST 288   // fp8 row stride (bytes): 72 words -> conflict-free ds_read_b64

typedef _Float16 f16;
typedef _Float16 f16x2 __attribute__((ext_vector_type(2)));
typedef _Float16 f16x4 __attribute__((ext_vector_type(4)));
typedef _Float16 f16x8 __attribute__((ext_vector_type(8)));
typedef float    f32x4 __attribute__((ext_vector_type(4)));

// ws float offsets
#define OFF_WATT    0u         // [512][320] f32 W_att^T (setup intermediate)
#define OFF_WCOMBT  163840u    // [512][256] f32 W_comb^T (intermediate)
#define OFF_P1B     294912u    // [81][320]
#define OFF_P2B     320832u    // [81][256]
#define OFF_Q2T     341568u    // [81][256] f32 (intermediate)
#define OFF_Q2PE    362304u    // [256]
#define OFF_PE      362560u    // [256]
#define OFF_Q2TPH   362816u    // f16 [21][1024] panels of Q2T (10752 floats)
#define OFF_WCAT8   373568u    // fp8 [64 nt][16 kw][64 lane][8] gates weights x64 (131072 floats)
#define OFF_WATTM   504640u    // f16 [20 nt][8 kw][64 lane][8] attn-h weights (40960 floats)
#define OFF_WFCPH   545600u    // f16 [32][81][8] W_fc^T (10368 floats)
#define OFF_LOSS    555968u    // [1024]

static __device__ __forceinline__ float rcpf(float x)  { return __builtin_amdgcn_rcpf(x); }
static __device__ __forceinline__ float sigm(float x)  { return rcpf(1.f + __expf(-x)); }
static __device__ __forceinline__ float tanhf_(float x){ return 1.f - 2.f * rcpf(1.f + __expf(2.f * x)); }

static __device__ __forceinline__ unsigned char f2fp8(float x) {
#if __has_builtin(__builtin_amdgcn_cvt_pk_fp8_f32)
    return (unsigned char)(__builtin_amdgcn_cvt_pk_fp8_f32(x, 0.f, 0, false) & 0xff);
#else
    __hip_fp8_e4m3 t(x);
    return (unsigned char)t.__x;
#endif
}

static __device__ __forceinline__ float dot2(f16x2 a, f16x2 b, float c) {
#if __has_builtin(__builtin_amdgcn_fdot2)
    return __builtin_amdgcn_fdot2(a, b, c, false);
#else
    return c + (float)a[0] * (float)b[0] + (float)a[1] * (float)b[1];
#endif
}
#define DOT4(wf4, af4, acc) { \
    acc = dot2(__builtin_bit_cast(f16x2, (wf4).x), __builtin_bit_cast(f16x2, (af4).x), acc); \
    acc = dot2(__builtin_bit_cast(f16x2, (wf4).y), __builtin_bit_cast(f16x2, (af4).y), acc); \
    acc = dot2(__builtin_bit_cast(f16x2, (wf4).z), __builtin_bit_cast(f16x2, (af4).z), acc); \
    acc = dot2(__builtin_bit_cast(f16x2, (wf4).w), __builtin_bit_cast(f16x2, (af4).w), acc); }

static __device__ __forceinline__ void ctr_add(int* p) {
    if ((threadIdx.x & 63) == 0)
        __hip_atomic_fetch_add(p, 1, __ATOMIC_RELEASE, __HIP_MEMORY_SCOPE_WORKGROUP);
}
static __device__ __forceinline__ void ctr_spin(int* p, int target) {
    while (__hip_atomic_load(p, __ATOMIC_ACQUIRE, __HIP_MEMORY_SCOPE_WORKGROUP) < target)
        __builtin_amdgcn_s_sleep(1);
}

// ---------------- setup kernels ----------------
__global__ __launch_bounds__(128) void k_pe(float* __restrict__ pe) {
    const int i = threadIdx.x;
    const float arg  = (float)(2 * i) * (-0.035977892078031968f);
    const float divf = expf(arg) * 300.0f;
    pe[2 * i]     = (float)sin((double)divf);
    pe[2 * i + 1] = (float)cos((double)divf);
}
__global__ __launch_bounds__(256) void k_tr_att(const float* __restrict__ W, float* __restrict__ WT) {
    const int i = blockIdx.x * 256 + threadIdx.x;
    if (i < 512 * LA) { const int k = i / LA, l = i - k * LA; WT[i] = W[l * 512 + k]; }
}
__global__ __launch_bounds__(256) void k_tr_comb(const float* __restrict__ W, float* __restrict__ WT) {
    const int i = blockIdx.x * 256 + threadIdx.x;
    const int k = i >> 8, j = i & 255;
    if (i < 512 * NH) WT[i] = W[j * 512 + k];
}
__global__ __launch_bounds__(320) void k_p1b(const float* __restrict__ emb, const float* __restrict__ WATT,
                                             const float* __restrict__ b_att, float* __restrict__ P1B) {
    __shared__ float e[NH];
    const int v = blockIdx.x, tid = threadIdx.x;
    if (tid < NH) e[tid] = emb[v * NH + tid];
    __syncthreads();
    float a = b_att[tid];
    #pragma unroll 8
    for (int k = 0; k < NH; ++k) a += e[k] * WATT[k * LA + tid];
    P1B[v * LA + tid] = a;
}
__global__ __launch_bounds__(256) void k_p2q(const float* __restrict__ emb, const float* __restrict__ WCOMBT,
                                             const float* __restrict__ b_comb,
                                             float* __restrict__ P2B, float* __restrict__ Q2T) {
    __shared__ float e[NH];
    const int v = blockIdx.x, tid = threadIdx.x;
    e[tid] = emb[v * NH + tid];
    __syncthreads();
    float a = b_comb[tid], q = 0.f;
    #pragma unroll 8
    for (int k = 0; k < NH; ++k) {
        a += e[k] * WCOMBT[k * NH + tid];
        q += e[k] * WCOMBT[(NH + k) * NH + tid];
    }
    P2B[v * NH + tid] = a;
    Q2T[v * NH + tid] = q;
}
__global__ __launch_bounds__(256) void k_q2pe(const float* __restrict__ pe, const float* __restrict__ WCOMBT,
                                              float* __restrict__ Q2PE) {
    __shared__ float e[NH];
    const int tid = threadIdx.x;
    e[tid] = pe[tid];
    __syncthreads();
    float q = 0.f;
    #pragma unroll 8
    for (int k = 0; k < NH; ++k) q += e[k] * WCOMBT[(NH + k) * NH + tid];
    Q2PE[tid] = q;
}
__global__ __launch_bounds__(256) void k_pan_q2h(const float* __restrict__ Q2T, f16* __restrict__ P) {
    const int i = blockIdx.x * 256 + threadIdx.x;
    if (i < NV * NH) {
        const int v = i >> 8, j = i & 255;
        P[(v >> 2) * 1024 + j * 4 + (v & 3)] = (f16)Q2T[v * NH + j];
    }
}
// gates weights -> fp8 MFMA B-frag order, stored as e4m3(64*w).
// B[k][c], k in [0,512), c = j*4+g. lane l holds k = kw*32 + (l>>4)*8 + jj, col = nt*16 + (l&15).
__global__ __launch_bounds__(256) void k_pan_cat_8(const float* __restrict__ Wih, const float* __restrict__ Whh,
                                                   unsigned char* __restrict__ P) {
    const int i = blockIdx.x * 256 + threadIdx.x;
    if (i < 512 * 1024) {
        const int k = i >> 10, c = i & 1023, jcol = c >> 2, g = c & 3;
        const float v = (k < NH) ? Wih[(g * NH + jcol) * NH + k] : Whh[(g * NH + jcol) * NH + (k - NH)];
        const int nt = c >> 4, kw = k >> 5, kr = k & 31;
        const int l = (kr >> 3) * 16 + (c & 15), jj = kr & 7;
        P[nt * 8192 + kw * 512 + l * 8 + jj] = f2fp8(v * 64.f);
    }
}
__global__ __launch_bounds__(256) void k_pan_att_m(const float* __restrict__ W, f16* __restrict__ P) {
    const int i = blockIdx.x * 256 + threadIdx.x;
    if (i < 256 * LA) {
        const int k = i / LA, lcol = i - k * LA;
        const float v = W[lcol * 512 + 256 + k];
        const int nt = lcol >> 4, kw = k >> 5, kr = k & 31;
        const int l = (kr >> 3) * 16 + (lcol & 15), jj = kr & 7;
        P[nt * 4096 + kw * 512 + l * 8 + jj] = (f16)v;
    }
}
__global__ __launch_bounds__(256) void k_pan_fc_h(const float* __restrict__ W, f16* __restrict__ P) {
    const int i = blockIdx.x * 256 + threadIdx.x;
    if (i < 256 * NV) {
        const int k = i / NV, v = i - k * NV;
        P[(k >> 3) * 648 + v * 8 + (k & 7)] = (f16)W[v * NH + k];
    }
}

// ---------------- persistent decoder: 256 blocks x 1024 thr, 4 rows/block, wave-specialized ----------------
__global__ __launch_bounds__(1024, 4) void k_run(
    const int* __restrict__ enc, const int* __restrict__ tgt,
    const f16* __restrict__ WATTM, const float* __restrict__ P1B,
    const float* __restrict__ P2B, const f16* __restrict__ Q2TPH,
    const float* __restrict__ Q2PE, const unsigned char* __restrict__ WCAT8,
    const f16* __restrict__ WFCPH,
    const float* __restrict__ bih, const float* __restrict__ bhh,
    const float* __restrict__ bfc, float* __restrict__ out_logits,
    float* __restrict__ loss_out)
{
    __shared__ __attribute__((aligned(16))) f16 hbufh[2][4][HST];          // h f16 (attn + fc)
    __shared__ __attribute__((aligned(16))) unsigned char hb8[2][4][BST];  // h fp8 x16 (gates A)
    __shared__ __attribute__((aligned(16))) unsigned char xh8[4][BST];     // x fp8 x16 (gates A)
    __shared__ __attribute__((aligned(16))) f16 q2lds[21 * 1024];
    __shared__ float q2pe_lds[NH];
    __shared__ float p_s[4][324];
    __shared__ float gex[4][1040];
    __shared__ float bsum_lds[1024];
    __shared__ float cw_s[4][84];
    __shared__ float lg_s[4][84];
    __shared__ float sm_inv[4], sm_s300[4];
    __shared__ unsigned short idx16[4][SL];
    __shared__ unsigned short cnt16[4][NV];
    __shared__ unsigned short offs16[4][NV + 1];
    __shared__ float bfc_s[84];
    __shared__ float loss_s[4];
    __shared__ int   xd_s[4];
    __shared__ int   c_aP1, c_aSM, c_xr, c_gd, c_hr;

    const int tid  = threadIdx.x;
    const int wid  = tid >> 6;
    const int lane = tid & 63;
    const int mrow = lane & 15;
    const int arow4 = mrow & 3;
    const int khi  = lane >> 4;
    const int row0 = blockIdx.x * 4;

    // ---- one-time init (barriers allowed) ----
    {
        f16* hz = &hbufh[0][0][0];
        for (int i = tid; i < 2 * 4 * HST; i += 1024) hz[i] = (f16)0.f;
        unsigned char* h8 = &hb8[0][0][0];
        for (int i = tid; i < 2 * 4 * BST; i += 1024) h8[i] = 0;
        unsigned char* x8 = &xh8[0][0];
        for (int i = tid; i < 4 * BST; i += 1024) x8[i] = 0;
    }
    { const int c = tid, j = c >> 2, g = c & 3; bsum_lds[c] = bih[g * NH + j] + bhh[g * NH + j]; }
    if (tid < 84) bfc_s[tid] = (tid < NV) ? bfc[tid] : 0.f;
    if (tid < 4) { xd_s[tid] = 1; loss_s[tid] = 0.f; }
    if (tid < 4 * 84) cw_s[tid / 84][tid % 84] = 0.f;
    if (tid == 0) { c_aP1 = 0; c_aSM = 0; c_xr = 0; c_gd = 0; c_hr = 0; }
    for (int i = tid; i < 2688; i += 1024)
        ((f16x8*)q2lds)[i] = ((const f16x8*)Q2TPH)[i];
    if (tid < NH) q2pe_lds[tid] = Q2PE[tid];
    {
        const int rg = tid >> 8, jg = tid & 255;
        const int* __restrict__ encr = enc + (row0 + rg) * SL;
        if (jg < NV) {
            int c = 0;
            for (int l = 0; l < SL; ++l) c += (encr[l] == jg);
            cnt16[rg][jg] = (unsigned short)c;
        }
        __syncthreads();
        if (jg == 0) {
            int o = 0; offs16[rg][0] = 0;
            for (int v = 0; v < NV; ++v) { o += cnt16[rg][v]; offs16[rg][v + 1] = (unsigned short)o; }
        }
        __syncthreads();
        if (jg < NV) {
            int o = offs16[rg][jg];
            for (int l = 0; l < SL; ++l) if (encr[l] == jg) idx16[rg][o++] = (unsigned short)l;
        }
    }
    __syncthreads();

    if (wid >= 8) {
        // ================= GATES WAVES (wid 8..15): fp8 stream + MFMA =================
        const int nt0 = (wid - 8) * 8;
        for (int t = 0; t < NT; ++t) {
            const int pb = t & 1;
            ctr_spin(&c_hr, 8 * t);
            f32x4 acc[8];
            #pragma unroll
            for (int i = 0; i < 8; ++i) acc[i] = (f32x4){0.f, 0.f, 0.f, 0.f};
            {   // h-half: kw 8..15
                const unsigned char* __restrict__ hr8 = &hb8[pb][arow4][khi * 8];
                const unsigned char* __restrict__ B   = WCAT8 + (size_t)nt0 * 8192 + lane * 8;
                #pragma unroll 2
                for (int kw = 8; kw < 16; ++kw) {
                    const long a = *(const long*)(hr8 + (kw - 8) * 32);
                    const unsigned char* bp = B + kw * 512;
                    #pragma unroll
                    for (int i = 0; i < 8; ++i)
                        acc[i] = __builtin_amdgcn_mfma_f32_16x16x32_fp8_fp8(
                            a, *(const long*)(bp + (size_t)i * 8192), acc[i], 0, 0, 0);
                }
            }
            ctr_spin(&c_xr, 8 * (t + 1));
            {   // x-half: kw 0..7
                const unsigned char* __restrict__ xr8 = &xh8[arow4][khi * 8];
                const unsigned char* __restrict__ B   = WCAT8 + (size_t)nt0 * 8192 + lane * 8;
                #pragma unroll 2
                for (int kw = 0; kw < 8; ++kw) {
                    const long a = *(const long*)(xr8 + kw * 32);
                    const unsigned char* bp = B + kw * 512;
                    #pragma unroll
                    for (int i = 0; i < 8; ++i)
                        acc[i] = __builtin_amdgcn_mfma_f32_16x16x32_fp8_fp8(
                            a, *(const long*)(bp + (size_t)i * 8192), acc[i], 0, 0, 0);
                }
            }
            if (lane < 16) {
                #pragma unroll
                for (int i = 0; i < 8; ++i) {
                    const int cc = (nt0 + i) * 16 + mrow;
                    #pragma unroll
                    for (int j = 0; j < 4; ++j) gex[j][cc] = acc[i][j] * 0.0009765625f; // 1/1024
                }
            }
            ctr_add(&c_gd);
        }
    } else {
        // ================= ATTENTION / VALU WAVES (wid 0..7) =================
        const int w = wid;
        float creg0 = 0.f, creg1 = 0.f;    // rows tid>>8 and (tid>>8)+2, unit tid&255
        for (int t = 0; t < NT; ++t) {
            const int pb = t & 1;
            ctr_spin(&c_hr, 8 * t);
            // ---- P1: attention MFMA (f16), wave w owns nt {w, w+8, (+w+16 if w<4)} ----
            {
                f32x4 z0 = {0.f,0.f,0.f,0.f}, z1 = {0.f,0.f,0.f,0.f}, z2 = {0.f,0.f,0.f,0.f};
                const bool three = (w < 4);
                const f16* __restrict__ B0 = WATTM + w * 4096 + lane * 8;
                const f16* __restrict__ B1 = WATTM + (8 + w) * 4096 + lane * 8;
                const f16* __restrict__ B2 = WATTM + (16 + w) * 4096 + lane * 8;
                const f16* __restrict__ hr = &hbufh[pb][arow4][khi * 8];
                #pragma unroll 2
                for (int kw = 0; kw < 8; ++kw) {
                    const f16x8 a = *(const f16x8*)(hr + kw * 32);
                    z0 = __builtin_amdgcn_mfma_f32_16x16x32_f16(a, *(const f16x8*)(B0 + kw * 512), z0, 0, 0, 0);
                    z1 = __builtin_amdgcn_mfma_f32_16x16x32_f16(a, *(const f16x8*)(B1 + kw * 512), z1, 0, 0, 0);
                    if (three)
                        z2 = __builtin_amdgcn_mfma_f32_16x16x32_f16(a, *(const f16x8*)(B2 + kw * 512), z2, 0, 0, 0);
                }
                if (lane < 16) {
                    #pragma unroll
                    for (int i = 0; i < 4; ++i) {
                        p_s[i][w * 16 + mrow]       = z0[i];
                        p_s[i][(8 + w) * 16 + mrow] = z1[i];
                        if (three) p_s[i][(16 + w) * 16 + mrow] = z2[i];
                    }
                }
            }
            ctr_add(&c_aP1);
            // ---- softmax + binning: waves 0-3, one row each ----
            if (w < 4) {
                ctr_spin(&c_aP1, 8 * (t + 1));
                const int r = w;
                const float* __restrict__ P1r = P1B + xd_s[r] * LA;
                float zv[5];
                #pragma unroll
                for (int i = 0; i < 5; ++i) zv[i] = p_s[r][lane + 64 * i] + P1r[lane + 64 * i];
                float m = fmaxf(fmaxf(fmaxf(zv[0], zv[1]), fmaxf(zv[2], zv[3])), zv[4]);
                #pragma unroll
                for (int off = 32; off > 0; off >>= 1) m = fmaxf(m, __shfl_xor(m, off));
                float sa = 0.f;
                #pragma unroll
                for (int i = 0; i < 5; ++i) {
                    zv[i] = __expf(zv[i] - m);
                    p_s[r][lane + 64 * i] = zv[i];
                    sa += zv[i];
                }
                float sh = (lane >= 44) ? zv[4] : 0.f;     // l in [300,320)
                #pragma unroll
                for (int off = 32; off > 0; off >>= 1) { sa += __shfl_xor(sa, off); sh += __shfl_xor(sh, off); }
                {   // bins 0..63
                    const int o0 = offs16[r][lane], o1 = offs16[r][lane + 1];
                    float s = 0.f;
                    for (int o = o0; o < o1; ++o) s += p_s[r][idx16[r][o]];
                    cw_s[r][lane] = s;
                }
                if (lane < NV - 64) {   // bins 64..80
                    const int b2 = 64 + lane;
                    const int o0 = offs16[r][b2], o1 = offs16[r][b2 + 1];
                    float s = 0.f;
                    for (int o = o0; o < o1; ++o) s += p_s[r][idx16[r][o]];
                    cw_s[r][b2] = s;
                }
                if (lane == 0) { sm_inv[r] = 1.0f / sa; sm_s300[r] = sa - sh; }
                ctr_add(&c_aSM);
            }
            ctr_spin(&c_aSM, 4 * (t + 1));
            // ---- phase 2: x (1024 items over 512 threads; q2 f16 LDS, cw f32) ----
            #pragma unroll
            for (int half = 0; half < 2; ++half) {
                const int item = tid + half * 512;
                const int r = item >> 8, j = item & 255;
                const float inv = sm_inv[r], s300 = sm_s300[r];
                float acc = s300 * q2pe_lds[j];
                const float* __restrict__ cwr = cw_s[r];
                #pragma unroll 5
                for (int vb = 0; vb < 20; ++vb) {
                    const f16x4 qv = *(const f16x4*)(q2lds + vb * 1024 + j * 4);
                    const float4 cv = *(const float4*)(cwr + vb * 4);
                    acc += (float)qv[0] * cv.x + (float)qv[1] * cv.y
                         + (float)qv[2] * cv.z + (float)qv[3] * cv.w;
                }
                acc += cwr[80] * (float)q2lds[20 * 1024 + j * 4];
                const float xv = fmaxf(P2B[xd_s[r] * NH + j] + acc * inv, 0.f);
                xh8[r][j] = f2fp8(xv * 16.f);
            }
            ctr_add(&c_xr);
            // ---- LSTM pointwise (needs gates done) ----
            ctr_spin(&c_gd, 8 * (t + 1));
            {
                const int r0 = tid >> 8, u = tid & 255;
                const float4 g0 = *(const float4*)(&gex[r0][u * 4]);
                const float4 b4 = *(const float4*)(&bsum_lds[u * 4]);
                creg0 = sigm(g0.y + b4.y) * creg0 + sigm(g0.x + b4.x) * tanhf_(g0.z + b4.z);
                const float h0v = sigm(g0.w + b4.w) * tanhf_(creg0);
                hbufh[pb ^ 1][r0][u] = (f16)h0v;
                hb8[pb ^ 1][r0][u] = f2fp8(h0v * 16.f);
                const float4 g1 = *(const float4*)(&gex[r0 + 2][u * 4]);
                creg1 = sigm(g1.y + b4.y) * creg1 + sigm(g1.x + b4.x) * tanhf_(g1.z + b4.z);
                const float h1v = sigm(g1.w + b4.w) * tanhf_(creg1);
                hbufh[pb ^ 1][r0 + 2][u] = (f16)h1v;
                hb8[pb ^ 1][r0 + 2][u] = f2fp8(h1v * 16.f);
            }
            ctr_add(&c_hr);
            // ---- fc + argmax + loss: waves 0-3, one row each (overlaps gates h-half of t+1) ----
            if (w < 4) {
                ctr_spin(&c_hr, 8 * (t + 1));
                const int r = w;
                const f16* __restrict__ hr = &hbufh[pb ^ 1][r][0];
                const int v1 = lane;
                float a1 = 0.f;
                {
                    const f16* __restrict__ wp = WFCPH + v1 * 8;
                    #pragma unroll 4
                    for (int kb = 0; kb < 32; ++kb) {
                        const float4 wv = *(const float4*)(wp + kb * 648);
                        const float4 hv = *(const float4*)(hr + kb * 8);
                        DOT4(wv, hv, a1);
                    }
                }
                const float lv1 = a1 + bfc_s[v1];
                lg_s[r][v1] = lv1;
                if (v1 < NV) out_logits[((size_t)t * NB + row0 + r) * NV + v1] = lv1;
                if (lane < NV - 64) {
                    const int v2 = 64 + lane;
                    float a2 = 0.f;
                    const f16* __restrict__ wp = WFCPH + v2 * 8;
                    #pragma unroll 4
                    for (int kb = 0; kb < 32; ++kb) {
                        const float4 wv = *(const float4*)(wp + kb * 648);
                        const float4 hv = *(const float4*)(hr + kb * 8);
                        DOT4(wv, hv, a2);
                    }
                    const float lv2 = a2 + bfc_s[v2];
                    lg_s[r][v2] = lv2;
                    out_logits[((size_t)t * NB + row0 + r) * NV + v2] = lv2;
                }
                float v0 = lg_s[r][lane]; int i0 = lane;
                if (lane < NV - 64) {
                    const float vb = lg_s[r][64 + lane];
                    if (vb > v0) { v0 = vb; i0 = 64 + lane; }
                }
                #pragma unroll
                for (int off = 32; off > 0; off >>= 1) {
                    const float vo = __shfl_xor(v0, off);
                    const int   io = __shfl_xor(i0, off);
                    if (vo > v0 || (vo == v0 && io < i0)) { v0 = vo; i0 = io; }
                }
                float e = __expf(lg_s[r][lane] - v0);
                if (lane < NV - 64) e += __expf(lg_s[r][64 + lane] - v0);
                #pragma unroll
                for (int off = 32; off > 0; off >>= 1) e += __shfl_xor(e, off);
                if (lane == 0) {
                    const int y = tgt[(row0 + r) * NT + t];
                    loss_s[r] += -(lg_s[r][y] - v0 - logf(e));
                    xd_s[r] = i0;
                }
            }
        }
        if (tid < 4) loss_out[row0 + tid] = loss_s[tid];
    }
}

// ---------------- final mean ----------------
__global__ __launch_bounds__(256) void k_final(const float* __restrict__ loss, float* __restrict__ dst) {
    const int tid = threadIdx.x;
    float v = loss[tid] + loss[tid + 256] + loss[tid + 512] + loss[tid + 768];
    #pragma unroll
    for (int o = 32; o > 0; o >>= 1) v += __shfl_xor(v, o);
    __shared__ float red[4];
    if ((tid & 63) == 0) red[tid >> 6] = v;
    __syncthreads();
    if (tid == 0) dst[0] = (red[0] + red[1] + red[2] + red[3]) / (float)(NB * NT);
}

extern "C" void kernel_launch(void* const* d_in, const int* in_sizes, int n_in,
                              void* d_out, int out_size, void* d_ws, size_t ws_size,
                              hipStream_t stream) {
    const int*   enc    = (const int*)d_in[0];
    const int*   tgt    = (const int*)d_in[1];
    const float* emb    = (const float*)d_in[3];
    const float* W_att  = (const float*)d_in[4];
    const float* b_att  = (const float*)d_in[5];
    const float* W_comb = (const float*)d_in[6];
    const float* b_comb = (const float*)d_in[7];
    const float* W_ih   = (const float*)d_in[8];
    const float* b_ih   = (const float*)d_in[9];
    const float* W_hh   = (const float*)d_in[10];
    const float* b_hh   = (const float*)d_in[11];
    const float* W_fc   = (const float*)d_in[12];
    const float* b_fc   = (const float*)d_in[13];

    float* ws  = (float*)d_ws;
    float* out = (float*)d_out;
    unsigned char* WCAT8 = (unsigned char*)(ws + OFF_WCAT8);
    f16* WATTM  = (f16*)(ws + OFF_WATTM);
    f16* WFCPH  = (f16*)(ws + OFF_WFCPH);
    f16* Q2TPH  = (f16*)(ws + OFF_Q2TPH);

    hipLaunchKernelGGL(k_pe,      dim3(1),    dim3(128), 0, stream, ws + OFF_PE);
    hipLaunchKernelGGL(k_tr_att,  dim3(640),  dim3(256), 0, stream, W_att,  ws + OFF_WATT);
    hipLaunchKernelGGL(k_tr_comb, dim3(512),  dim3(256), 0, stream, W_comb, ws + OFF_WCOMBT);
    hipLaunchKernelGGL(k_p1b,     dim3(81),   dim3(320), 0, stream, emb, ws + OFF_WATT, b_att, ws + OFF_P1B);
    hipLaunchKernelGGL(k_p2q,     dim3(81),   dim3(256), 0, stream, emb, ws + OFF_WCOMBT, b_comb,
                       ws + OFF_P2B, ws + OFF_Q2T);
    hipLaunchKernelGGL(k_q2pe,    dim3(1),    dim3(256), 0, stream, ws + OFF_PE, ws + OFF_WCOMBT, ws + OFF_Q2PE);
    hipLaunchKernelGGL(k_pan_q2h, dim3(81),   dim3(256), 0, stream, ws + OFF_Q2T, Q2TPH);
    hipLaunchKernelGGL(k_pan_cat_8, dim3(2048), dim3(256), 0, stream, W_ih, W_hh, WCAT8);
    hipLaunchKernelGGL(k_pan_att_m, dim3(320),  dim3(256), 0, stream, W_att, WATTM);
    hipLaunchKernelGGL(k_pan_fc_h,  dim3(81),   dim3(256), 0, stream, W_fc, WFCPH);

    hipLaunchKernelGGL(k_run, dim3(256), dim3(1024), 0, stream,
                       enc, tgt,
                       WATTM, ws + OFF_P1B, ws + OFF_P2B,
                       Q2TPH, ws + OFF_Q2PE, WCAT8, WFCPH,
                       b_ih, b_hh, b_fc,
                       out, ws + OFF_LOSS);

    hipLaunchKernelGGL(k_final, dim3(1), dim3(256), 0, stream, ws + OFF_LOSS, out + (out_size - 1));
}

// Round 14
// 2567.873 us; speedup vs baseline: 1.1380x; 1.0760x over previous
//
#include <hip/hip_runtime.h>

#define NB 1024
#define SL 300
#define NT 150
#define NH 256
#define LA 320
#define NV 81
#define HST 272   // f16 row stride in halves: 136 words ≡ 8 (mod 32) -> uniform 2-way (free) MFMA A-reads

typedef _Float16 f16;
typedef _Float16 f16x2 __attribute__((ext_vector_type(2)));
typedef _Float16 f16x4 __attribute__((ext_vector_type(4)));
typedef _Float16 f16x8 __attribute__((ext_vector_type(8)));
typedef float    f32x4 __attribute__((ext_vector_type(4)));

// ws float offsets
#define OFF_WATT    0u         // [512][320] f32 W_att^T (setup intermediate)
#define OFF_WCOMBT  163840u    // [512][256] f32 W_comb^T (intermediate)
#define OFF_P1B     294912u    // [81][320]  f32 emb@W_att[:,:256]^T + b_att
#define OFF_P2B     320832u    // [81][256]  f32 emb@W_comb[:,:256]^T + b_comb
#define OFF_Q2T     341568u    // [81][256]  f32 (intermediate)
#define OFF_Q2PE    362304u    // [256]
#define OFF_PE      362560u    // [256]
#define OFF_Q2TPH   362816u    // f16 [21][1024] panels of Q2T (fits in old Q2TP region)
#define OFF_WCATM   384320u    // f16 MFMA-frag gates weights [64 nt][16 kw][64 lane][8]
#define OFF_WATTM   646464u    // f16 MFMA-frag attn-h weights [20 nt][8 kw][64 lane][8]
#define OFF_WFCPH   687424u    // f16 [32][81][8] W_fc^T (dot2 layout)
#define OFF_LOSS    697792u    // [1024]

static __device__ __forceinline__ float rcpf(float x)  { return __builtin_amdgcn_rcpf(x); }
static __device__ __forceinline__ float sigm(float x)  { return rcpf(1.f + __expf(-x)); }
static __device__ __forceinline__ float tanhf_(float x){ return 1.f - 2.f * rcpf(1.f + __expf(2.f * x)); }

static __device__ __forceinline__ float dot2(f16x2 a, f16x2 b, float c) {
#if __has_builtin(__builtin_amdgcn_fdot2)
    return __builtin_amdgcn_fdot2(a, b, c, false);
#else
    return c + (float)a[0] * (float)b[0] + (float)a[1] * (float)b[1];
#endif
}
#define DOT4(wf4, af4, acc) { \
    acc = dot2(__builtin_bit_cast(f16x2, (wf4).x), __builtin_bit_cast(f16x2, (af4).x), acc); \
    acc = dot2(__builtin_bit_cast(f16x2, (wf4).y), __builtin_bit_cast(f16x2, (af4).y), acc); \
    acc = dot2(__builtin_bit_cast(f16x2, (wf4).z), __builtin_bit_cast(f16x2, (af4).z), acc); \
    acc = dot2(__builtin_bit_cast(f16x2, (wf4).w), __builtin_bit_cast(f16x2, (af4).w), acc); }

// ---------------- setup kernels ----------------
__global__ __launch_bounds__(128) void k_pe(float* __restrict__ pe) {
    const int i = threadIdx.x;
    const float arg  = (float)(2 * i) * (-0.035977892078031968f);
    const float divf = expf(arg) * 300.0f;
    pe[2 * i]     = (float)sin((double)divf);
    pe[2 * i + 1] = (float)cos((double)divf);
}
__global__ __launch_bounds__(256) void k_tr_att(const float* __restrict__ W, float* __restrict__ WT) {
    const int i = blockIdx.x * 256 + threadIdx.x;
    if (i < 512 * LA) { const int k = i / LA, l = i - k * LA; WT[i] = W[l * 512 + k]; }
}
__global__ __launch_bounds__(256) void k_tr_comb(const float* __restrict__ W, float* __restrict__ WT) {
    const int i = blockIdx.x * 256 + threadIdx.x;
    const int k = i >> 8, j = i & 255;
    if (i < 512 * NH) WT[i] = W[j * 512 + k];
}
__global__ __launch_bounds__(320) void k_p1b(const float* __restrict__ emb, const float* __restrict__ WATT,
                                             const float* __restrict__ b_att, float* __restrict__ P1B) {
    __shared__ float e[NH];
    const int v = blockIdx.x, tid = threadIdx.x;
    if (tid < NH) e[tid] = emb[v * NH + tid];
    __syncthreads();
    float a = b_att[tid];
    #pragma unroll 8
    for (int k = 0; k < NH; ++k) a += e[k] * WATT[k * LA + tid];
    P1B[v * LA + tid] = a;
}
__global__ __launch_bounds__(256) void k_p2q(const float* __restrict__ emb, const float* __restrict__ WCOMBT,
                                             const float* __restrict__ b_comb,
                                             float* __restrict__ P2B, float* __restrict__ Q2T) {
    __shared__ float e[NH];
    const int v = blockIdx.x, tid = threadIdx.x;
    e[tid] = emb[v * NH + tid];
    __syncthreads();
    float a = b_comb[tid], q = 0.f;
    #pragma unroll 8
    for (int k = 0; k < NH; ++k) {
        a += e[k] * WCOMBT[k * NH + tid];
        q += e[k] * WCOMBT[(NH + k) * NH + tid];
    }
    P2B[v * NH + tid] = a;
    Q2T[v * NH + tid] = q;
}
__global__ __launch_bounds__(256) void k_q2pe(const float* __restrict__ pe, const float* __restrict__ WCOMBT,
                                              float* __restrict__ Q2PE) {
    __shared__ float e[NH];
    const int tid = threadIdx.x;
    e[tid] = pe[tid];
    __syncthreads();
    float q = 0.f;
    #pragma unroll 8
    for (int k = 0; k < NH; ++k) q += e[k] * WCOMBT[(NH + k) * NH + tid];
    Q2PE[tid] = q;
}
// Q2T -> 4v panels f16: elem (v, j) at half-index [(v>>2)*1024 + j*4 + (v&3)]
__global__ __launch_bounds__(256) void k_pan_q2h(const float* __restrict__ Q2T, f16* __restrict__ P) {
    const int i = blockIdx.x * 256 + threadIdx.x;
    if (i < NV * NH) {
        const int v = i >> 8, j = i & 255;
        P[(v >> 2) * 1024 + j * 4 + (v & 3)] = (f16)Q2T[v * NH + j];
    }
}
// gates weights -> f16 MFMA B-frag order
__global__ __launch_bounds__(256) void k_pan_cat_m(const float* __restrict__ Wih, const float* __restrict__ Whh,
                                                   f16* __restrict__ P) {
    const int i = blockIdx.x * 256 + threadIdx.x;
    if (i < 512 * 1024) {
        const int k = i >> 10, c = i & 1023, jcol = c >> 2, g = c & 3;
        const float v = (k < NH) ? Wih[(g * NH + jcol) * NH + k] : Whh[(g * NH + jcol) * NH + (k - NH)];
        const int nt = c >> 4, kw = k >> 5, kr = k & 31;
        const int l = (kr >> 3) * 16 + (c & 15), jj = kr & 7;
        P[nt * 8192 + kw * 512 + l * 8 + jj] = (f16)v;
    }
}
// attn-h weights -> f16 MFMA B-frag order
__global__ __launch_bounds__(256) void k_pan_att_m(const float* __restrict__ W, f16* __restrict__ P) {
    const int i = blockIdx.x * 256 + threadIdx.x;
    if (i < 256 * LA) {
        const int k = i / LA, lcol = i - k * LA;
        const float v = W[lcol * 512 + 256 + k];
        const int nt = lcol >> 4, kw = k >> 5, kr = k & 31;
        const int l = (kr >> 3) * 16 + (lcol & 15), jj = kr & 7;
        P[nt * 4096 + kw * 512 + l * 8 + jj] = (f16)v;
    }
}
// W_fc^T f16 dot2 layout
__global__ __launch_bounds__(256) void k_pan_fc_h(const float* __restrict__ W, f16* __restrict__ P) {
    const int i = blockIdx.x * 256 + threadIdx.x;
    if (i < 256 * NV) {
        const int k = i / NV, v = i - k * NV;
        P[(k >> 3) * 648 + v * 8 + (k & 7)] = (f16)W[v * NH + k];
    }
}

// ---------------- persistent decoder: 256 blocks x 1024 threads, 4 rows/block ----------------
__global__ __launch_bounds__(1024, 4) void k_run(
    const int* __restrict__ enc, const int* __restrict__ tgt,
    const f16* __restrict__ WATTM, const float* __restrict__ P1B,
    const float* __restrict__ P2B, const f16* __restrict__ Q2TPH,
    const float* __restrict__ Q2PE, const f16* __restrict__ WCATM,
    const f16* __restrict__ WFCPH,
    const float* __restrict__ bih, const float* __restrict__ bhh,
    const float* __restrict__ bfc, float* __restrict__ out_logits,
    float* __restrict__ loss_out)
{
    __shared__ __attribute__((aligned(16))) f16 hbufh[2][4][HST];
    __shared__ __attribute__((aligned(16))) f16 xh[4][HST];
    __shared__ __attribute__((aligned(16))) f16 q2lds[21 * 1024];
    __shared__ float q2pe_lds[NH];
    __shared__ float p_s[4][324];          // raw z then exp
    __shared__ float gex[4][1024];         // gate exchange (no bias)
    __shared__ float bsum_lds[1024];
    __shared__ float cw_s[4][84];
    __shared__ float lg_s[4][84];
    __shared__ float lgpart[2][4][84];
    __shared__ unsigned short idx16[4][SL];
    __shared__ unsigned short cnt16[4][NV];
    __shared__ unsigned short offs16[4][NV + 1];
    __shared__ float redM[4][4];
    __shared__ float redS[4][4][2];
    __shared__ float bfc_s[84];
    __shared__ float loss_s[4];
    __shared__ int   xd_s[4];

    const int tid  = threadIdx.x;
    const int r4   = tid & 3;
    const int q4   = tid >> 2;      // 0..255
    const int rowg = tid >> 8;
    const int jg   = tid & 255;
    const int wid  = tid >> 6;
    const int lane = tid & 63;
    const int mrow = lane & 15;
    const int arow4 = mrow & 3;
    const int khi  = lane >> 4;
    const int row0 = blockIdx.x * 4;

    // ---- init ----
    {
        f16* hz = &hbufh[0][0][0];
        for (int i = tid; i < 2 * 4 * HST; i += 1024) hz[i] = (f16)0.f;
        f16* xz = &xh[0][0];
        for (int i = tid; i < 4 * HST; i += 1024) xz[i] = (f16)0.f;
    }
    { const int j = tid >> 2, g = tid & 3; bsum_lds[tid] = bih[g * NH + j] + bhh[g * NH + j]; }
    if (tid < 84) bfc_s[tid] = (tid < NV) ? bfc[tid] : 0.f;
    if (tid < 4 * 84) { cw_s[tid / 84][tid % 84] = 0.f; }
    if (tid < 4) { xd_s[tid] = 1; loss_s[tid] = 0.f; }
    for (int i = tid; i < 2688; i += 1024)
        ((f16x8*)q2lds)[i] = ((const f16x8*)Q2TPH)[i];
    if (tid < NH) q2pe_lds[tid] = Q2PE[tid];
    const int* __restrict__ encr = enc + (row0 + rowg) * SL;
    if (jg < NV) {
        int c = 0;
        for (int l = 0; l < SL; ++l) c += (encr[l] == jg);
        cnt16[rowg][jg] = (unsigned short)c;
    }
    __syncthreads();
    if (jg == 0) {
        int o = 0; offs16[rowg][0] = 0;
        for (int v = 0; v < NV; ++v) { o += cnt16[rowg][v]; offs16[rowg][v + 1] = (unsigned short)o; }
    }
    __syncthreads();
    if (jg < NV) {
        int o = offs16[rowg][jg];
        for (int l = 0; l < SL; ++l) if (encr[l] == jg) idx16[rowg][o++] = (unsigned short)l;
    }
    __syncthreads();

    float creg = 0.f;   // cell state for (rowg, jg)

    for (int t = 0; t < NT; ++t) {
        const int pb = t & 1;

        // ---- phase 1: attention z via MFMA (wave=ntile; waves 0-3 take a 2nd ntile) ----
        {
            f32x4 za0 = {0.f, 0.f, 0.f, 0.f}, za1 = {0.f, 0.f, 0.f, 0.f};
            const bool two = (wid < 4);
            const f16* __restrict__ B0 = WATTM + wid * 4096 + lane * 8;
            const f16* __restrict__ B1 = WATTM + (16 + wid) * 4096 + lane * 8;
            const f16* __restrict__ hr = &hbufh[pb][arow4][khi * 8];
            #pragma unroll 4
            for (int kw = 0; kw < 8; ++kw) {
                const f16x8 a = *(const f16x8*)(hr + kw * 32);
                const f16x8 b0 = *(const f16x8*)(B0 + kw * 512);
                za0 = __builtin_amdgcn_mfma_f32_16x16x32_f16(a, b0, za0, 0, 0, 0);
                if (two) {
                    const f16x8 b1 = *(const f16x8*)(B1 + kw * 512);
                    za1 = __builtin_amdgcn_mfma_f32_16x16x32_f16(a, b1, za1, 0, 0, 0);
                }
            }
            if (lane < 16) {
                #pragma unroll
                for (int i = 0; i < 4; ++i) p_s[i][wid * 16 + mrow] = za0[i];
                if (two) {
                    #pragma unroll
                    for (int i = 0; i < 4; ++i) p_s[i][256 + wid * 16 + mrow] = za1[i];
                }
            }
        }
        __syncthreads();                                   // B1

        // ---- softmax stats (adds P1B here) ----
        {
            const float* __restrict__ P1r = P1B + xd_s[rowg] * LA;
            const float za = p_s[rowg][jg] + P1r[jg];
            const float zb = (jg < 64) ? (p_s[rowg][256 + jg] + P1r[256 + jg]) : -3.4e38f;
            float m = fmaxf(za, zb);
            #pragma unroll
            for (int off = 32; off > 0; off >>= 1) m = fmaxf(m, __shfl_xor(m, off));
            if (lane == 0) redM[rowg][wid & 3] = m;
            __syncthreads();                               // B2
            const float M = fmaxf(fmaxf(redM[rowg][0], redM[rowg][1]),
                                  fmaxf(redM[rowg][2], redM[rowg][3]));
            const float ea = __expf(za - M);
            p_s[rowg][jg] = ea;
            float eb = 0.f;
            if (jg < 64) { eb = __expf(zb - M); p_s[rowg][256 + jg] = eb; }
            float sa = ea + eb;
            float sh = (jg >= 44 && jg < 64) ? eb : 0.f;   // l in [300,320)
            #pragma unroll
            for (int off = 32; off > 0; off >>= 1) { sa += __shfl_xor(sa, off); sh += __shfl_xor(sh, off); }
            if (lane == 0) { redS[rowg][wid & 3][0] = sa; redS[rowg][wid & 3][1] = sh; }
        }
        __syncthreads();                                   // B3

        // ---- vocab binning ----
        if (jg < NV) {
            const int o0 = offs16[rowg][jg], o1 = offs16[rowg][jg + 1];
            float s = 0.f;
            for (int o = o0; o < o1; ++o) s += p_s[rowg][idx16[rowg][o]];
            cw_s[rowg][jg] = s;
        }
        __syncthreads();                                   // B4

        // ---- phase 2: x = relu(P2B[xv] + (Q2T.cw + s300*q2pe)/SA), store f16 ----
        {
            const int j = q4;
            const float SA  = redS[r4][0][0] + redS[r4][1][0] + redS[r4][2][0] + redS[r4][3][0];
            const float SH  = redS[r4][0][1] + redS[r4][1][1] + redS[r4][2][1] + redS[r4][3][1];
            const float inv = 1.0f / SA;
            const float s300 = SA - SH;
            float acc = s300 * q2pe_lds[j];
            const float* __restrict__ cwr = cw_s[r4];
            #pragma unroll 5
            for (int vb = 0; vb < 20; ++vb) {
                const f16x4 qv = *(const f16x4*)(q2lds + vb * 1024 + j * 4);
                const float4 cv = *(const float4*)(cwr + vb * 4);
                acc += (float)qv[0] * cv.x + (float)qv[1] * cv.y
                     + (float)qv[2] * cv.z + (float)qv[3] * cv.w;
            }
            acc += cwr[80] * (float)q2lds[20 * 1024 + j * 4];
            const int xv = xd_s[r4];
            xh[r4][j] = (f16)fmaxf(P2B[xv * NH + j] + acc * inv, 0.f);
        }
        __syncthreads();                                   // B5

        // ---- phase 3: gates GEMM via MFMA (wave = 4 ntiles of 16 cols; 16 kw) ----
        {
            f32x4 acc0 = {0.f,0.f,0.f,0.f}, acc1 = {0.f,0.f,0.f,0.f};
            f32x4 acc2 = {0.f,0.f,0.f,0.f}, acc3 = {0.f,0.f,0.f,0.f};
            const f16* __restrict__ BG = WCATM + (size_t)wid * 4 * 8192 + lane * 8;
            const f16* __restrict__ xr = &xh[arow4][khi * 8];
            const f16* __restrict__ hr = &hbufh[pb][arow4][khi * 8];
            #pragma unroll 4
            for (int kw = 0; kw < 16; ++kw) {
                const f16x8 a = (kw < 8) ? *(const f16x8*)(xr + kw * 32)
                                         : *(const f16x8*)(hr + (kw - 8) * 32);
                const f16* bp = BG + kw * 512;
                const f16x8 b0 = *(const f16x8*)(bp);
                const f16x8 b1 = *(const f16x8*)(bp + 8192);
                const f16x8 b2 = *(const f16x8*)(bp + 16384);
                const f16x8 b3 = *(const f16x8*)(bp + 24576);
                acc0 = __builtin_amdgcn_mfma_f32_16x16x32_f16(a, b0, acc0, 0, 0, 0);
                acc1 = __builtin_amdgcn_mfma_f32_16x16x32_f16(a, b1, acc1, 0, 0, 0);
                acc2 = __builtin_amdgcn_mfma_f32_16x16x32_f16(a, b2, acc2, 0, 0, 0);
                acc3 = __builtin_amdgcn_mfma_f32_16x16x32_f16(a, b3, acc3, 0, 0, 0);
            }
            if (lane < 16) {
                const int c0 = wid * 64 + mrow;
                #pragma unroll
                for (int i = 0; i < 4; ++i) {
                    gex[i][c0]      = acc0[i];
                    gex[i][c0 + 16] = acc1[i];
                    gex[i][c0 + 32] = acc2[i];
                    gex[i][c0 + 48] = acc3[i];
                }
            }
        }
        __syncthreads();                                   // B6

        // ---- LSTM pointwise (adds bias here) ----
        {
            const float4 g4 = *(const float4*)(gex[rowg] + 4 * jg);   // i,f,g,o
            const float4 b4 = *(const float4*)(bsum_lds + 4 * jg);
            creg = sigm(g4.y + b4.y) * creg + sigm(g4.x + b4.x) * tanhf_(g4.z + b4.z);
            hbufh[pb ^ 1][rowg][jg] = (f16)(sigm(g4.w + b4.w) * tanhf_(creg));
        }
        __syncthreads();                                   // B7

        // ---- phase 4: fc logits f16 dot2 (k-split x2) ----
        if (q4 < 2 * NV) {
            const int v  = (q4 < NV) ? q4 : q4 - NV;
            const int ks = (q4 >= NV) ? 1 : 0;
            const f16* __restrict__ hr = &hbufh[pb ^ 1][r4][ks * 128];
            const f16* __restrict__ wp = WFCPH + (ks * 16) * 648 + v * 8;
            float acc = 0.f;
            #pragma unroll 4
            for (int kb = 0; kb < 16; ++kb) {
                const float4 w  = *(const float4*)(wp + kb * 648);
                const float4 h4 = *(const float4*)(hr + kb * 8);
                DOT4(w, h4, acc);
            }
            lgpart[ks][r4][v] = acc;
        }
        __syncthreads();                                   // B8
        if (tid < 4 * NV) {
            const int rr = tid / NV, v = tid - rr * NV;
            const float lv = lgpart[0][rr][v] + lgpart[1][rr][v] + bfc_s[v];
            lg_s[rr][v] = lv;
            out_logits[((size_t)t * NB + row0 + rr) * NV + v] = lv;
        }
        __syncthreads();                                   // B9

        // ---- argmax (first-max) + loss ----
        if (wid < 4) {
            const int rr = wid;
            float v0 = lg_s[rr][lane]; int i0 = lane;
            if (lane < NV - 64) {
                const float vb = lg_s[rr][64 + lane];
                if (vb > v0) { v0 = vb; i0 = 64 + lane; }
            }
            #pragma unroll
            for (int off = 32; off > 0; off >>= 1) {
                const float vo = __shfl_xor(v0, off);
                const int   io = __shfl_xor(i0, off);
                if (vo > v0 || (vo == v0 && io < i0)) { v0 = vo; i0 = io; }
            }
            float e = __expf(lg_s[rr][lane] - v0);
            if (lane < NV - 64) e += __expf(lg_s[rr][64 + lane] - v0);
            #pragma unroll
            for (int off = 32; off > 0; off >>= 1) e += __shfl_xor(e, off);
            if (lane == 0) {
                const int y = tgt[(row0 + rr) * NT + t];
                loss_s[rr] += -(lg_s[rr][y] - v0 - logf(e));
                xd_s[rr] = i0;
            }
        }
        __syncthreads();                                   // B10
    }

    if (tid < 4) loss_out[row0 + tid] = loss_s[tid];
}

// ---------------- final mean ----------------
__global__ __launch_bounds__(256) void k_final(const float* __restrict__ loss, float* __restrict__ dst) {
    const int tid = threadIdx.x;
    float v = loss[tid] + loss[tid + 256] + loss[tid + 512] + loss[tid + 768];
    #pragma unroll
    for (int o = 32; o > 0; o >>= 1) v += __shfl_xor(v, o);
    __shared__ float red[4];
    if ((tid & 63) == 0) red[tid >> 6] = v;
    __syncthreads();
    if (tid == 0) dst[0] = (red[0] + red[1] + red[2] + red[3]) / (float)(NB * NT);
}

extern "C" void kernel_launch(void* const* d_in, const int* in_sizes, int n_in,
                              void* d_out, int out_size, void* d_ws, size_t ws_size,
                              hipStream_t stream) {
    const int*   enc    = (const int*)d_in[0];
    const int*   tgt    = (const int*)d_in[1];
    const float* emb    = (const float*)d_in[3];
    const float* W_att  = (const float*)d_in[4];
    const float* b_att  = (const float*)d_in[5];
    const float* W_comb = (const float*)d_in[6];
    const float* b_comb = (const float*)d_in[7];
    const float* W_ih   = (const float*)d_in[8];
    const float* b_ih   = (const float*)d_in[9];
    const float* W_hh   = (const float*)d_in[10];
    const float* b_hh   = (const float*)d_in[11];
    const float* W_fc   = (const float*)d_in[12];
    const float* b_fc   = (const float*)d_in[13];

    float* ws  = (float*)d_ws;
    float* out = (float*)d_out;
    f16* WCATM = (f16*)(ws + OFF_WCATM);
    f16* WATTM = (f16*)(ws + OFF_WATTM);
    f16* WFCPH = (f16*)(ws + OFF_WFCPH);
    f16* Q2TPH = (f16*)(ws + OFF_Q2TPH);

    hipLaunchKernelGGL(k_pe,      dim3(1),    dim3(128), 0, stream, ws + OFF_PE);
    hipLaunchKernelGGL(k_tr_att,  dim3(640),  dim3(256), 0, stream, W_att,  ws + OFF_WATT);
    hipLaunchKernelGGL(k_tr_comb, dim3(512),  dim3(256), 0, stream, W_comb, ws + OFF_WCOMBT);
    hipLaunchKernelGGL(k_p1b,     dim3(81),   dim3(320), 0, stream, emb, ws + OFF_WATT, b_att, ws + OFF_P1B);
    hipLaunchKernelGGL(k_p2q,     dim3(81),   dim3(256), 0, stream, emb, ws + OFF_WCOMBT, b_comb,
                       ws + OFF_P2B, ws + OFF_Q2T);
    hipLaunchKernelGGL(k_q2pe,    dim3(1),    dim3(256), 0, stream, ws + OFF_PE, ws + OFF_WCOMBT, ws + OFF_Q2PE);
    hipLaunchKernelGGL(k_pan_q2h, dim3(81),   dim3(256), 0, stream, ws + OFF_Q2T, Q2TPH);
    hipLaunchKernelGGL(k_pan_cat_m, dim3(2048), dim3(256), 0, stream, W_ih, W_hh, WCATM);
    hipLaunchKernelGGL(k_pan_att_m, dim3(320),  dim3(256), 0, stream, W_att, WATTM);
    hipLaunchKernelGGL(k_pan_fc_h,  dim3(81),   dim3(256), 0, stream, W_fc, WFCPH);

    hipLaunchKernelGGL(k_run, dim3(256), dim3(1024), 0, stream,
                       enc, tgt,
                       WATTM, ws + OFF_P1B, ws + OFF_P2B,
                       Q2TPH, ws + OFF_Q2PE, WCATM, WFCPH,
                       b_ih, b_hh, b_fc,
                       out, ws + OFF_LOSS);

    hipLaunchKernelGGL(k_final, dim3(1), dim3(256), 0, stream, ws + OFF_LOSS, out + (out_size - 1));
}

// Round 15
// 2566.491 us; speedup vs baseline: 1.1386x; 1.0005x over previous
//
#include <hip/hip_runtime.h>
#include <hip/hip_fp8.h>

#define NB 1024
#define SL 300
#define NT 150
#define NH 256
#define LA 320
#define NV 81
#define HST 272   // f16 row stride in halves: 136 words ≡ 8 (mod 32) -> conflict-free MFMA A-reads
#define BST 288   // fp8 row stride in bytes: 72 words ≡ 8 (mod 32) -> conflict-free fp8 A-reads

typedef _Float16 f16;
typedef _Float16 f16x2 __attribute__((ext_vector_type(2)));
typedef _Float16 f16x4 __attribute__((ext_vector_type(4)));
typedef _Float16 f16x8 __attribute__((ext_vector_type(8)));
typedef float    f32x4 __attribute__((ext_vector_type(4)));

// ws float offsets
#define OFF_WATT    0u         // [512][320] f32 W_att^T (setup intermediate)
#define OFF_WCOMBT  163840u    // [512][256] f32 W_comb^T (intermediate)
#define OFF_P1B     294912u    // [81][320]
#define OFF_P2B     320832u    // [81][256]
#define OFF_Q2T     341568u    // [81][256] f32 (intermediate)
#define OFF_Q2PE    362304u    // [256]
#define OFF_PE      362560u    // [256]
#define OFF_Q2TPH   362816u    // f16 [21][1024] (10752 floats)
#define OFF_WCAT8   373568u    // fp8 [64 nt][16 kw][64 lane][8] x64 -> 524288 B = 131072 floats
#define OFF_WATTM   504640u    // f16 [20 nt][8 kw][64 lane][8] (40960 floats)
#define OFF_WFCPH   545600u    // f16 [32][81][8] (10368 floats)
#define OFF_LOSS    555968u    // [1024]

static __device__ __forceinline__ float rcpf(float x)  { return __builtin_amdgcn_rcpf(x); }
static __device__ __forceinline__ float sigm(float x)  { return rcpf(1.f + __expf(-x)); }
static __device__ __forceinline__ float tanhf_(float x){ return 1.f - 2.f * rcpf(1.f + __expf(2.f * x)); }

static __device__ __forceinline__ unsigned char f2fp8(float x) {
#if __has_builtin(__builtin_amdgcn_cvt_pk_fp8_f32)
    return (unsigned char)(__builtin_amdgcn_cvt_pk_fp8_f32(x, 0.f, 0, false) & 0xff);
#else
    __hip_fp8_e4m3 t(x);
    return (unsigned char)t.__x;
#endif
}

static __device__ __forceinline__ float dot2(f16x2 a, f16x2 b, float c) {
#if __has_builtin(__builtin_amdgcn_fdot2)
    return __builtin_amdgcn_fdot2(a, b, c, false);
#else
    return c + (float)a[0] * (float)b[0] + (float)a[1] * (float)b[1];
#endif
}
#define DOT4(wf4, af4, acc) { \
    acc = dot2(__builtin_bit_cast(f16x2, (wf4).x), __builtin_bit_cast(f16x2, (af4).x), acc); \
    acc = dot2(__builtin_bit_cast(f16x2, (wf4).y), __builtin_bit_cast(f16x2, (af4).y), acc); \
    acc = dot2(__builtin_bit_cast(f16x2, (wf4).z), __builtin_bit_cast(f16x2, (af4).z), acc); \
    acc = dot2(__builtin_bit_cast(f16x2, (wf4).w), __builtin_bit_cast(f16x2, (af4).w), acc); }

// ---------------- setup kernels ----------------
__global__ __launch_bounds__(128) void k_pe(float* __restrict__ pe) {
    const int i = threadIdx.x;
    const float arg  = (float)(2 * i) * (-0.035977892078031968f);
    const float divf = expf(arg) * 300.0f;
    pe[2 * i]     = (float)sin((double)divf);
    pe[2 * i + 1] = (float)cos((double)divf);
}
__global__ __launch_bounds__(256) void k_tr_att(const float* __restrict__ W, float* __restrict__ WT) {
    const int i = blockIdx.x * 256 + threadIdx.x;
    if (i < 512 * LA) { const int k = i / LA, l = i - k * LA; WT[i] = W[l * 512 + k]; }
}
__global__ __launch_bounds__(256) void k_tr_comb(const float* __restrict__ W, float* __restrict__ WT) {
    const int i = blockIdx.x * 256 + threadIdx.x;
    const int k = i >> 8, j = i & 255;
    if (i < 512 * NH) WT[i] = W[j * 512 + k];
}
__global__ __launch_bounds__(320) void k_p1b(const float* __restrict__ emb, const float* __restrict__ WATT,
                                             const float* __restrict__ b_att, float* __restrict__ P1B) {
    __shared__ float e[NH];
    const int v = blockIdx.x, tid = threadIdx.x;
    if (tid < NH) e[tid] = emb[v * NH + tid];
    __syncthreads();
    float a = b_att[tid];
    #pragma unroll 8
    for (int k = 0; k < NH; ++k) a += e[k] * WATT[k * LA + tid];
    P1B[v * LA + tid] = a;
}
__global__ __launch_bounds__(256) void k_p2q(const float* __restrict__ emb, const float* __restrict__ WCOMBT,
                                             const float* __restrict__ b_comb,
                                             float* __restrict__ P2B, float* __restrict__ Q2T) {
    __shared__ float e[NH];
    const int v = blockIdx.x, tid = threadIdx.x;
    e[tid] = emb[v * NH + tid];
    __syncthreads();
    float a = b_comb[tid], q = 0.f;
    #pragma unroll 8
    for (int k = 0; k < NH; ++k) {
        a += e[k] * WCOMBT[k * NH + tid];
        q += e[k] * WCOMBT[(NH + k) * NH + tid];
    }
    P2B[v * NH + tid] = a;
    Q2T[v * NH + tid] = q;
}
__global__ __launch_bounds__(256) void k_q2pe(const float* __restrict__ pe, const float* __restrict__ WCOMBT,
                                              float* __restrict__ Q2PE) {
    __shared__ float e[NH];
    const int tid = threadIdx.x;
    e[tid] = pe[tid];
    __syncthreads();
    float q = 0.f;
    #pragma unroll 8
    for (int k = 0; k < NH; ++k) q += e[k] * WCOMBT[(NH + k) * NH + tid];
    Q2PE[tid] = q;
}
__global__ __launch_bounds__(256) void k_pan_q2h(const float* __restrict__ Q2T, f16* __restrict__ P) {
    const int i = blockIdx.x * 256 + threadIdx.x;
    if (i < NV * NH) {
        const int v = i >> 8, j = i & 255;
        P[(v >> 2) * 1024 + j * 4 + (v & 3)] = (f16)Q2T[v * NH + j];
    }
}
// gates weights -> fp8 MFMA B-frags, stored e4m3(64*w)
__global__ __launch_bounds__(256) void k_pan_cat_8(const float* __restrict__ Wih, const float* __restrict__ Whh,
                                                   unsigned char* __restrict__ P) {
    const int i = blockIdx.x * 256 + threadIdx.x;
    if (i < 512 * 1024) {
        const int k = i >> 10, c = i & 1023, jcol = c >> 2, g = c & 3;
        const float v = (k < NH) ? Wih[(g * NH + jcol) * NH + k] : Whh[(g * NH + jcol) * NH + (k - NH)];
        const int nt = c >> 4, kw = k >> 5, kr = k & 31;
        const int l = (kr >> 3) * 16 + (c & 15), jj = kr & 7;
        P[nt * 8192 + kw * 512 + l * 8 + jj] = f2fp8(v * 64.f);
    }
}
// attn-h weights -> f16 MFMA B-frags
__global__ __launch_bounds__(256) void k_pan_att_m(const float* __restrict__ W, f16* __restrict__ P) {
    const int i = blockIdx.x * 256 + threadIdx.x;
    if (i < 256 * LA) {
        const int k = i / LA, lcol = i - k * LA;
        const float v = W[lcol * 512 + 256 + k];
        const int nt = lcol >> 4, kw = k >> 5, kr = k & 31;
        const int l = (kr >> 3) * 16 + (lcol & 15), jj = kr & 7;
        P[nt * 4096 + kw * 512 + l * 8 + jj] = (f16)v;
    }
}
__global__ __launch_bounds__(256) void k_pan_fc_h(const float* __restrict__ W, f16* __restrict__ P) {
    const int i = blockIdx.x * 256 + threadIdx.x;
    if (i < 256 * NV) {
        const int k = i / NV, v = i - k * NV;
        P[(k >> 3) * 648 + v * 8 + (k & 7)] = (f16)W[v * NH + k];
    }
}

// ---------------- persistent decoder: 256 blocks x 1024 threads, 4 rows/block ----------------
__global__ __launch_bounds__(1024, 4) void k_run(
    const int* __restrict__ enc, const int* __restrict__ tgt,
    const f16* __restrict__ WATTM, const float* __restrict__ P1B,
    const float* __restrict__ P2B, const f16* __restrict__ Q2TPH,
    const float* __restrict__ Q2PE, const unsigned char* __restrict__ WCAT8,
    const f16* __restrict__ WFCPH,
    const float* __restrict__ bih, const float* __restrict__ bhh,
    const float* __restrict__ bfc, float* __restrict__ out_logits,
    float* __restrict__ loss_out)
{
    __shared__ __attribute__((aligned(16))) f16 hbufh[2][4][HST];          // h f16 (attn + fc A)
    __shared__ __attribute__((aligned(16))) unsigned char hb8[2][4][BST];  // h fp8 x16 (gates A)
    __shared__ __attribute__((aligned(16))) unsigned char xh8[4][BST];     // x fp8 x16 (gates A)
    __shared__ __attribute__((aligned(16))) f16 q2lds[21 * 1024];
    __shared__ float q2pe_lds[NH];
    __shared__ float p_s[4][324];          // raw z then exp
    __shared__ float gex[4][1024];         // gate exchange (no bias)
    __shared__ float bsum_lds[1024];
    __shared__ float cw_s[4][84];
    __shared__ float lg_s[4][84];
    __shared__ float lgpart[2][4][84];
    __shared__ unsigned short idx16[4][SL];
    __shared__ unsigned short cnt16[4][NV];
    __shared__ unsigned short offs16[4][NV + 1];
    __shared__ float redM[4][4];
    __shared__ float redS[4][4][2];
    __shared__ float bfc_s[84];
    __shared__ float loss_s[4];
    __shared__ int   xd_s[4];

    const int tid  = threadIdx.x;
    const int r4   = tid & 3;
    const int q4   = tid >> 2;      // 0..255
    const int rowg = tid >> 8;
    const int jg   = tid & 255;
    const int wid  = tid >> 6;
    const int lane = tid & 63;
    const int mrow = lane & 15;
    const int arow4 = mrow & 3;
    const int khi  = lane >> 4;
    const int row0 = blockIdx.x * 4;

    // ---- init ----
    {
        f16* hz = &hbufh[0][0][0];
        for (int i = tid; i < 2 * 4 * HST; i += 1024) hz[i] = (f16)0.f;
        unsigned char* h8 = &hb8[0][0][0];
        for (int i = tid; i < 2 * 4 * BST; i += 1024) h8[i] = 0;
        unsigned char* x8 = &xh8[0][0];
        for (int i = tid; i < 4 * BST; i += 1024) x8[i] = 0;
    }
    { const int j = tid >> 2, g = tid & 3; bsum_lds[tid] = bih[g * NH + j] + bhh[g * NH + j]; }
    if (tid < 84) bfc_s[tid] = (tid < NV) ? bfc[tid] : 0.f;
    if (tid < 4 * 84) { cw_s[tid / 84][tid % 84] = 0.f; }
    if (tid < 4) { xd_s[tid] = 1; loss_s[tid] = 0.f; }
    for (int i = tid; i < 2688; i += 1024)
        ((f16x8*)q2lds)[i] = ((const f16x8*)Q2TPH)[i];
    if (tid < NH) q2pe_lds[tid] = Q2PE[tid];
    const int* __restrict__ encr = enc + (row0 + rowg) * SL;
    if (jg < NV) {
        int c = 0;
        for (int l = 0; l < SL; ++l) c += (encr[l] == jg);
        cnt16[rowg][jg] = (unsigned short)c;
    }
    __syncthreads();
    if (jg == 0) {
        int o = 0; offs16[rowg][0] = 0;
        for (int v = 0; v < NV; ++v) { o += cnt16[rowg][v]; offs16[rowg][v + 1] = (unsigned short)o; }
    }
    __syncthreads();
    if (jg < NV) {
        int o = offs16[rowg][jg];
        for (int l = 0; l < SL; ++l) if (encr[l] == jg) idx16[rowg][o++] = (unsigned short)l;
    }
    __syncthreads();

    float creg = 0.f;   // cell state for (rowg, jg)

    for (int t = 0; t < NT; ++t) {
        const int pb = t & 1;

        // ---- phase 1: attention z via MFMA f16 (wave=ntile; waves 0-3 take a 2nd ntile) ----
        {
            f32x4 za0 = {0.f, 0.f, 0.f, 0.f}, za1 = {0.f, 0.f, 0.f, 0.f};
            const bool two = (wid < 4);
            const f16* __restrict__ B0 = WATTM + wid * 4096 + lane * 8;
            const f16* __restrict__ B1 = WATTM + (16 + wid) * 4096 + lane * 8;
            const f16* __restrict__ hr = &hbufh[pb][arow4][khi * 8];
            #pragma unroll 4
            for (int kw = 0; kw < 8; ++kw) {
                const f16x8 a = *(const f16x8*)(hr + kw * 32);
                const f16x8 b0 = *(const f16x8*)(B0 + kw * 512);
                za0 = __builtin_amdgcn_mfma_f32_16x16x32_f16(a, b0, za0, 0, 0, 0);
                if (two) {
                    const f16x8 b1 = *(const f16x8*)(B1 + kw * 512);
                    za1 = __builtin_amdgcn_mfma_f32_16x16x32_f16(a, b1, za1, 0, 0, 0);
                }
            }
            if (lane < 16) {
                #pragma unroll
                for (int i = 0; i < 4; ++i) p_s[i][wid * 16 + mrow] = za0[i];
                if (two) {
                    #pragma unroll
                    for (int i = 0; i < 4; ++i) p_s[i][256 + wid * 16 + mrow] = za1[i];
                }
            }
        }
        __syncthreads();                                   // B1

        // ---- softmax stats (adds P1B here) ----
        {
            const float* __restrict__ P1r = P1B + xd_s[rowg] * LA;
            const float za = p_s[rowg][jg] + P1r[jg];
            const float zb = (jg < 64) ? (p_s[rowg][256 + jg] + P1r[256 + jg]) : -3.4e38f;
            float m = fmaxf(za, zb);
            #pragma unroll
            for (int off = 32; off > 0; off >>= 1) m = fmaxf(m, __shfl_xor(m, off));
            if (lane == 0) redM[rowg][wid & 3] = m;
            __syncthreads();                               // B2
            const float M = fmaxf(fmaxf(redM[rowg][0], redM[rowg][1]),
                                  fmaxf(redM[rowg][2], redM[rowg][3]));
            const float ea = __expf(za - M);
            p_s[rowg][jg] = ea;
            float eb = 0.f;
            if (jg < 64) { eb = __expf(zb - M); p_s[rowg][256 + jg] = eb; }
            float sa = ea + eb;
            float sh = (jg >= 44 && jg < 64) ? eb : 0.f;   // l in [300,320)
            #pragma unroll
            for (int off = 32; off > 0; off >>= 1) { sa += __shfl_xor(sa, off); sh += __shfl_xor(sh, off); }
            if (lane == 0) { redS[rowg][wid & 3][0] = sa; redS[rowg][wid & 3][1] = sh; }
        }
        __syncthreads();                                   // B3

        // ---- vocab binning ----
        if (jg < NV) {
            const int o0 = offs16[rowg][jg], o1 = offs16[rowg][jg + 1];
            float s = 0.f;
            for (int o = o0; o < o1; ++o) s += p_s[rowg][idx16[rowg][o]];
            cw_s[rowg][jg] = s;
        }
        __syncthreads();                                   // B4

        // ---- phase 2: x = relu(P2B[xv] + (Q2T.cw + s300*q2pe)/SA), store fp8 x16 ----
        {
            const int j = q4;
            const float SA  = redS[r4][0][0] + redS[r4][1][0] + redS[r4][2][0] + redS[r4][3][0];
            const float SH  = redS[r4][0][1] + redS[r4][1][1] + redS[r4][2][1] + redS[r4][3][1];
            const float inv = 1.0f / SA;
            const float s300 = SA - SH;
            float acc = s300 * q2pe_lds[j];
            const float* __restrict__ cwr = cw_s[r4];
            #pragma unroll 5
            for (int vb = 0; vb < 20; ++vb) {
                const f16x4 qv = *(const f16x4*)(q2lds + vb * 1024 + j * 4);
                const float4 cv = *(const float4*)(cwr + vb * 4);
                acc += (float)qv[0] * cv.x + (float)qv[1] * cv.y
                     + (float)qv[2] * cv.z + (float)qv[3] * cv.w;
            }
            acc += cwr[80] * (float)q2lds[20 * 1024 + j * 4];
            const int xv = xd_s[r4];
            const float xval = fmaxf(P2B[xv * NH + j] + acc * inv, 0.f);
            xh8[r4][j] = f2fp8(xval * 16.f);
        }
        __syncthreads();                                   // B5

        // ---- phase 3: gates GEMM via fp8 MFMA (wave = 4 ntiles of 16 cols; 16 kw) ----
        {
            f32x4 acc0 = {0.f,0.f,0.f,0.f}, acc1 = {0.f,0.f,0.f,0.f};
            f32x4 acc2 = {0.f,0.f,0.f,0.f}, acc3 = {0.f,0.f,0.f,0.f};
            const unsigned char* __restrict__ BG = WCAT8 + (size_t)wid * 4 * 8192 + lane * 8;
            const unsigned char* __restrict__ xr8 = &xh8[arow4][khi * 8];
            const unsigned char* __restrict__ hr8 = &hb8[pb][arow4][khi * 8];
            #pragma unroll 4
            for (int kw = 0; kw < 16; ++kw) {
                const long a = (kw < 8) ? *(const long*)(xr8 + kw * 32)
                                        : *(const long*)(hr8 + (kw - 8) * 32);
                const unsigned char* bp = BG + kw * 512;
                acc0 = __builtin_amdgcn_mfma_f32_16x16x32_fp8_fp8(a, *(const long*)(bp),         acc0, 0, 0, 0);
                acc1 = __builtin_amdgcn_mfma_f32_16x16x32_fp8_fp8(a, *(const long*)(bp + 8192),  acc1, 0, 0, 0);
                acc2 = __builtin_amdgcn_mfma_f32_16x16x32_fp8_fp8(a, *(const long*)(bp + 16384), acc2, 0, 0, 0);
                acc3 = __builtin_amdgcn_mfma_f32_16x16x32_fp8_fp8(a, *(const long*)(bp + 24576), acc3, 0, 0, 0);
            }
            if (lane < 16) {
                const int c0 = wid * 64 + mrow;
                #pragma unroll
                for (int i = 0; i < 4; ++i) {
                    gex[i][c0]      = acc0[i] * 0.0009765625f;   // 1/1024 exact
                    gex[i][c0 + 16] = acc1[i] * 0.0009765625f;
                    gex[i][c0 + 32] = acc2[i] * 0.0009765625f;
                    gex[i][c0 + 48] = acc3[i] * 0.0009765625f;
                }
            }
        }
        __syncthreads();                                   // B6

        // ---- LSTM pointwise (adds bias here); writes h f16 + fp8 ----
        {
            const float4 g4 = *(const float4*)(gex[rowg] + 4 * jg);   // i,f,g,o
            const float4 b4 = *(const float4*)(bsum_lds + 4 * jg);
            creg = sigm(g4.y + b4.y) * creg + sigm(g4.x + b4.x) * tanhf_(g4.z + b4.z);
            const float hv = sigm(g4.w + b4.w) * tanhf_(creg);
            hbufh[pb ^ 1][rowg][jg] = (f16)hv;
            hb8[pb ^ 1][rowg][jg] = f2fp8(hv * 16.f);
        }
        __syncthreads();                                   // B7

        // ---- phase 4: fc logits f16 dot2 (k-split x2) ----
        if (q4 < 2 * NV) {
            const int v  = (q4 < NV) ? q4 : q4 - NV;
            const int ks = (q4 >= NV) ? 1 : 0;
            const f16* __restrict__ hr = &hbufh[pb ^ 1][r4][ks * 128];
            const f16* __restrict__ wp = WFCPH + (ks * 16) * 648 + v * 8;
            float acc = 0.f;
            #pragma unroll 4
            for (int kb = 0; kb < 16; ++kb) {
                const float4 w  = *(const float4*)(wp + kb * 648);
                const float4 h4 = *(const float4*)(hr + kb * 8);
                DOT4(w, h4, acc);
            }
            lgpart[ks][r4][v] = acc;
        }
        __syncthreads();                                   // B8
        if (tid < 4 * NV) {
            const int rr = tid / NV, v = tid - rr * NV;
            const float lv = lgpart[0][rr][v] + lgpart[1][rr][v] + bfc_s[v];
            lg_s[rr][v] = lv;
            out_logits[((size_t)t * NB + row0 + rr) * NV + v] = lv;
        }
        __syncthreads();                                   // B9

        // ---- argmax (first-max) + loss ----
        if (wid < 4) {
            const int rr = wid;
            float v0 = lg_s[rr][lane]; int i0 = lane;
            if (lane < NV - 64) {
                const float vb = lg_s[rr][64 + lane];
                if (vb > v0) { v0 = vb; i0 = 64 + lane; }
            }
            #pragma unroll
            for (int off = 32; off > 0; off >>= 1) {
                const float vo = __shfl_xor(v0, off);
                const int   io = __shfl_xor(i0, off);
                if (vo > v0 || (vo == v0 && io < i0)) { v0 = vo; i0 = io; }
            }
            float e = __expf(lg_s[rr][lane] - v0);
            if (lane < NV - 64) e += __expf(lg_s[rr][64 + lane] - v0);
            #pragma unroll
            for (int off = 32; off > 0; off >>= 1) e += __shfl_xor(e, off);
            if (lane == 0) {
                const int y = tgt[(row0 + rr) * NT + t];
                loss_s[rr] += -(lg_s[rr][y] - v0 - logf(e));
                xd_s[rr] = i0;
            }
        }
        __syncthreads();                                   // B10
    }

    if (tid < 4) loss_out[row0 + tid] = loss_s[tid];
}

// ---------------- final mean ----------------
__global__ __launch_bounds__(256) void k_final(const float* __restrict__ loss, float* __restrict__ dst) {
    const int tid = threadIdx.x;
    float v = loss[tid] + loss[tid + 256] + loss[tid + 512] + loss[tid + 768];
    #pragma unroll
    for (int o = 32; o > 0; o >>= 1) v += __shfl_xor(v, o);
    __shared__ float red[4];
    if ((tid & 63) == 0) red[tid >> 6] = v;
    __syncthreads();
    if (tid == 0) dst[0] = (red[0] + red[1] + red[2] + red[3]) / (float)(NB * NT);
}

extern "C" void kernel_launch(void* const* d_in, const int* in_sizes, int n_in,
                              void* d_out, int out_size, void* d_ws, size_t ws_size,
                              hipStream_t stream) {
    const int*   enc    = (const int*)d_in[0];
    const int*   tgt    = (const int*)d_in[1];
    const float* emb    = (const float*)d_in[3];
    const float* W_att  = (const float*)d_in[4];
    const float* b_att  = (const float*)d_in[5];
    const float* W_comb = (const float*)d_in[6];
    const float* b_comb = (const float*)d_in[7];
    const float* W_ih   = (const float*)d_in[8];
    const float* b_ih   = (const float*)d_in[9];
    const float* W_hh   = (const float*)d_in[10];
    const float* b_hh   = (const float*)d_in[11];
    const float* W_fc   = (const float*)d_in[12];
    const float* b_fc   = (const float*)d_in[13];

    float* ws  = (float*)d_ws;
    float* out = (float*)d_out;
    unsigned char* WCAT8 = (unsigned char*)(ws + OFF_WCAT8);
    f16* WATTM = (f16*)(ws + OFF_WATTM);
    f16* WFCPH = (f16*)(ws + OFF_WFCPH);
    f16* Q2TPH = (f16*)(ws + OFF_Q2TPH);

    hipLaunchKernelGGL(k_pe,      dim3(1),    dim3(128), 0, stream, ws + OFF_PE);
    hipLaunchKernelGGL(k_tr_att,  dim3(640),  dim3(256), 0, stream, W_att,  ws + OFF_WATT);
    hipLaunchKernelGGL(k_tr_comb, dim3(512),  dim3(256), 0, stream, W_comb, ws + OFF_WCOMBT);
    hipLaunchKernelGGL(k_p1b,     dim3(81),   dim3(320), 0, stream, emb, ws + OFF_WATT, b_att, ws + OFF_P1B);
    hipLaunchKernelGGL(k_p2q,     dim3(81),   dim3(256), 0, stream, emb, ws + OFF_WCOMBT, b_comb,
                       ws + OFF_P2B, ws + OFF_Q2T);
    hipLaunchKernelGGL(k_q2pe,    dim3(1),    dim3(256), 0, stream, ws + OFF_PE, ws + OFF_WCOMBT, ws + OFF_Q2PE);
    hipLaunchKernelGGL(k_pan_q2h, dim3(81),   dim3(256), 0, stream, ws + OFF_Q2T, Q2TPH);
    hipLaunchKernelGGL(k_pan_cat_8, dim3(2048), dim3(256), 0, stream, W_ih, W_hh, WCAT8);
    hipLaunchKernelGGL(k_pan_att_m, dim3(320),  dim3(256), 0, stream, W_att, WATTM);
    hipLaunchKernelGGL(k_pan_fc_h,  dim3(81),   dim3(256), 0, stream, W_fc, WFCPH);

    hipLaunchKernelGGL(k_run, dim3(256), dim3(1024), 0, stream,
                       enc, tgt,
                       WATTM, ws + OFF_P1B, ws + OFF_P2B,
                       Q2TPH, ws + OFF_Q2PE, WCAT8, WFCPH,
                       b_ih, b_hh, b_fc,
                       out, ws + OFF_LOSS);

    hipLaunchKernelGGL(k_final, dim3(1), dim3(256), 0, stream, ws + OFF_LOSS, out + (out_size - 1));
}